// Round 1
// baseline (4857.263 us; speedup 1.0000x reference)
//
#include <hip/hip_runtime.h>
#include <math.h>

#define BM 64
#define BF 64
#define BN 16

// MODE 0: pool/fc  — A is a shared [M,N] matrix, Bm is per-batch [B,N,F] (b from blockIdx.z)
// MODE 1: sconv    — A is per-batch X [B,M,Fi], rows gathered via idx [M,9]; Bm is shared W [N,F]
template <int MODE>
__global__ __launch_bounds__(256) void gemm_kernel(
    const float* __restrict__ A, const int* __restrict__ idx,
    const float* __restrict__ Bm, const float* __restrict__ bias,
    float* __restrict__ C, int M, int N, int F, int Fi, int doElu, int zeroLast)
{
    __shared__ __align__(16) float At[BN][BM + 4];  // [n][m] transposed
    __shared__ __align__(16) float Bt[BN][BF + 4];  // [n][f]

    const int b  = blockIdx.z;
    const int m0 = blockIdx.y * BM;
    const int f0 = blockIdx.x * BF;
    const int t  = threadIdx.x;
    const int tr = t >> 4;   // 0..15 row group
    const int tc = t & 15;   // 0..15 col group

    float acc[4][4] = {};

    const float* Bbase = (MODE == 0) ? (Bm + (size_t)b * N * F) : Bm;

    for (int n0 = 0; n0 < N; n0 += BN) {
        // A tile: 64 rows x 16 red-cols
        #pragma unroll
        for (int j = 0; j < 4; ++j) {
            int i  = t + j * 256;
            int ml = i >> 4, nl = i & 15;
            int mg = m0 + ml, ng = n0 + nl;
            float v = 0.f;
            if (mg < M && ng < N) {
                if (MODE == 0) {
                    v = A[(size_t)mg * N + ng];
                } else {
                    int k  = ng / Fi;
                    int fi = ng - k * Fi;
                    int vs = idx[mg * 9 + k];
                    v = A[((size_t)b * M + vs) * Fi + fi];
                }
            }
            At[nl][ml] = v;
        }
        // B tile: 16 red-rows x 64 cols
        #pragma unroll
        for (int j = 0; j < 4; ++j) {
            int i  = t + j * 256;
            int nl = i >> 6, fl = i & 63;
            int ng = n0 + nl, fg = f0 + fl;
            float v = 0.f;
            if (ng < N && fg < F) v = Bbase[(size_t)ng * F + fg];
            Bt[nl][fl] = v;
        }
        __syncthreads();
        #pragma unroll
        for (int kk = 0; kk < BN; ++kk) {
            float4 av = *(const float4*)&At[kk][tr * 4];
            float4 bv = *(const float4*)&Bt[kk][tc * 4];
            const float a4[4] = {av.x, av.y, av.z, av.w};
            const float b4[4] = {bv.x, bv.y, bv.z, bv.w};
            #pragma unroll
            for (int i = 0; i < 4; ++i)
                #pragma unroll
                for (int j = 0; j < 4; ++j)
                    acc[i][j] = fmaf(a4[i], b4[j], acc[i][j]);
        }
        __syncthreads();
    }

    #pragma unroll
    for (int i = 0; i < 4; ++i) {
        int mg = m0 + tr * 4 + i;
        if (mg >= M) continue;
        bool zl = zeroLast && (mg == M - 1);
        #pragma unroll
        for (int j = 0; j < 4; ++j) {
            int fg = f0 + tc * 4 + j;
            if (fg >= F) continue;
            float v = acc[i][j] + (bias ? bias[fg] : 0.f);
            if (doElu) v = (v > 0.f) ? v : expm1f(v);
            if (zl) v = 0.f;
            C[((size_t)b * M + mg) * F + fg] = v;
        }
    }
}

static inline void launch_op(int mode, const float* A, const int* idx, const float* Bm,
                             const float* bias, float* C, int M, int N, int F, int Fi,
                             int elu, int zl, int batch, hipStream_t stream)
{
    dim3 grid((F + BF - 1) / BF, (M + BM - 1) / BM, batch);
    if (mode == 0)
        gemm_kernel<0><<<grid, 256, 0, stream>>>(A, idx, Bm, bias, C, M, N, F, Fi, elu, zl);
    else
        gemm_kernel<1><<<grid, 256, 0, stream>>>(A, idx, Bm, bias, C, M, N, F, Fi, elu, zl);
}

extern "C" void kernel_launch(void* const* d_in, const int* in_sizes, int n_in,
                              void* d_out, int out_size, void* d_ws, size_t ws_size,
                              hipStream_t stream)
{
    const float* x  = (const float*)d_in[0];
    const int* s0 = (const int*)d_in[1];
    const int* s1 = (const int*)d_in[2];
    const int* s2 = (const int*)d_in[3];
    const int* s3 = (const int*)d_in[4];
    // D/U interleaved in setup_inputs: D0,U0,D1,U1,D2,U2,D3,U3
    const float* D0 = (const float*)d_in[5];
    const float* U0 = (const float*)d_in[6];
    const float* D1 = (const float*)d_in[7];
    const float* U1 = (const float*)d_in[8];
    const float* D2 = (const float*)d_in[9];
    const float* U2 = (const float*)d_in[10];
    const float* D3 = (const float*)d_in[11];
    const float* U3 = (const float*)d_in[12];
    const float* We0 = (const float*)d_in[13]; const float* be0 = (const float*)d_in[14];
    const float* We1 = (const float*)d_in[15]; const float* be1 = (const float*)d_in[16];
    const float* We2 = (const float*)d_in[17]; const float* be2 = (const float*)d_in[18];
    const float* We3 = (const float*)d_in[19]; const float* be3 = (const float*)d_in[20];
    const float* fceW = (const float*)d_in[21]; const float* fceb = (const float*)d_in[22];
    const float* fcdW = (const float*)d_in[23]; const float* fcdb = (const float*)d_in[24];
    const float* Wd0 = (const float*)d_in[25]; const float* bd0 = (const float*)d_in[26];
    const float* Wd1 = (const float*)d_in[27]; const float* bd1 = (const float*)d_in[28];
    const float* Wd2 = (const float*)d_in[29]; const float* bd2 = (const float*)d_in[30];
    const float* Wd3 = (const float*)d_in[31]; const float* bd3 = (const float*)d_in[32];

    // ping-pong scratch: bufA holds the big intermediates (max [64,5024,64]),
    // bufB only ever holds <= [64,1257,64]
    float* bufA = (float*)d_ws;
    float* bufB = bufA + (size_t)64 * 5024 * 64;
    float* out  = (float*)d_out;

    // ---- encoder ----
    launch_op(1, x,    s0, We0, be0, bufA, 5024,   27,  64,   3, 1, 1, 64, stream);
    launch_op(0, D0, nullptr, bufA, nullptr, bufB, 1257, 5024, 64, 0, 0, 0, 64, stream);
    launch_op(1, bufB, s1, We1, be1, bufA, 1257,  576,  64,  64, 1, 1, 64, stream);
    launch_op(0, D1, nullptr, bufA, nullptr, bufB,  315, 1257, 64, 0, 0, 0, 64, stream);
    launch_op(1, bufB, s2, We2, be2, bufA,  315,  576, 128,  64, 1, 1, 64, stream);
    launch_op(0, D2, nullptr, bufA, nullptr, bufB,   80,  315, 128, 0, 0, 0, 64, stream);
    launch_op(1, bufB, s3, We3, be3, bufA,   80, 1152, 256, 128, 1, 1, 64, stream);
    launch_op(0, D3, nullptr, bufA, nullptr, bufB,   21,   80, 256, 0, 0, 0, 64, stream);
    // ---- bottleneck FCs (batch=1, rows = batch elements) ----
    launch_op(0, bufB, nullptr, fceW, fceb, bufA, 64, 5376, 256, 0, 0, 0, 1, stream);   // z
    launch_op(0, bufA, nullptr, fcdW, fcdb, bufB, 64, 256, 5376, 0, 0, 0, 1, stream);   // [64,21,256]
    // ---- decoder ----
    launch_op(0, U3, nullptr, bufB, nullptr, bufA,   80,   21, 256, 0, 0, 0, 64, stream);
    launch_op(1, bufA, s3, Wd0, bd0, bufB,   80, 2304, 128, 256, 1, 1, 64, stream);
    launch_op(0, U2, nullptr, bufB, nullptr, bufA,  315,   80, 128, 0, 0, 0, 64, stream);
    launch_op(1, bufA, s2, Wd1, bd1, bufB,  315, 1152,  64, 128, 1, 1, 64, stream);
    launch_op(0, U1, nullptr, bufB, nullptr, bufA, 1257,  315,  64, 0, 0, 0, 64, stream);
    launch_op(1, bufA, s1, Wd2, bd2, bufB, 1257,  576,  64,  64, 1, 1, 64, stream);
    launch_op(0, U0, nullptr, bufB, nullptr, bufA, 5024, 1257,  64, 0, 0, 0, 64, stream);
    launch_op(1, bufA, s0, Wd3, bd3, out,  5024,  576,   3,  64, 0, 1, 64, stream);
}

// Round 3
// 1632.570 us; speedup vs baseline: 2.9752x; 2.9752x over previous
//
#include <hip/hip_runtime.h>
#include <math.h>

typedef __attribute__((ext_vector_type(8))) _Float16 half8;
typedef __attribute__((ext_vector_type(4))) float f32x4;

#define BM 128
#define BF 64
#define BK 32
#define SK 40   // LDS leading-dim pad: conflict-free-ish b128 reads

#define EPI_NAT 0
#define EPI_TR  1
#define EPI_FCD 2
#define EPI_OUT 3

typedef unsigned long long u64;

// AMODE: 0 = pool (A = dual-plane matrix [M][Np], B = single act plane)
//        1 = sconv gather, vector (A = act plane gathered via idx, Fi mult of 8; B dual weights)
//        2 = sconv gather, scalar (Fi=3 first layer; B dual weights)
//        3 = fc (A = single act plane [M][Np]; B dual weights)
template<int AMODE, int EPI>
__global__ __launch_bounds__(256) void gemm_k(
    const _Float16* __restrict__ Aw, u64 a_bs, u64 a_pl,
    const int* __restrict__ idx, int Fi, int Nreal,
    const _Float16* __restrict__ Bw, u64 b_bs, u64 b_pl,
    const float* __restrict__ bias,
    void* __restrict__ Cp, u64 c_bs, int Mp_out,
    int M, int Np, int F, int flags)   // flags: bit0 ELU, bit1 zeroLast
{
    constexpr bool ADUAL = (AMODE == 0);
    constexpr bool BDUAL = (AMODE != 0);
    constexpr int APL = ADUAL ? 2 : 1;
    constexpr int BPL = BDUAL ? 2 : 1;

    __shared__ _Float16 sA[APL][BM][SK];
    __shared__ _Float16 sB[BPL][BF][SK];

    const int t = threadIdx.x;
    const int b = blockIdx.z;
    const int m0 = blockIdx.y * BM;
    const int f0 = blockIdx.x * BF;
    const int lane = t & 63;
    const int wm = (t >> 6) >> 1;   // wave m index (0..1)
    const int wf = (t >> 6) & 1;    // wave f index (0..1)
    const int lm = lane & 15;
    const int lg = lane >> 4;

    const int nk = Np / BK;

    f32x4 acc[4][2];
    #pragma unroll
    for (int i = 0; i < 4; ++i)
        #pragma unroll
        for (int j = 0; j < 2; ++j)
            acc[i][j] = (f32x4)0.0f;

    // staging thread mapping — FULL BK coverage
    const int ar  = t >> 1;          // 0..127 (A row)
    const int acb = (t & 1) * 16;    // 0 or 16 (A col base; two half8 per thread)
    const int br  = t >> 2;          // 0..63  (B row)
    const int bcb = (t & 3) * 8;     // 0,8,16,24 (B col base; one half8 per plane)

    half8 zero8 = {(_Float16)0,(_Float16)0,(_Float16)0,(_Float16)0,
                   (_Float16)0,(_Float16)0,(_Float16)0,(_Float16)0};
    half8 rA0a = zero8, rA0b = zero8, rA1a = zero8, rA1b = zero8;
    half8 rB0 = zero8, rB1 = zero8;

    auto loadA = [&](int ks) {
        int n0 = ks * BK;
        int rg = m0 + ar;
        if (AMODE == 0) {
            if (rg < M) {
                const _Float16* p = Aw + (u64)rg * Np + n0 + acb;
                rA0a = *(const half8*)p;
                rA0b = *(const half8*)(p + 8);
                rA1a = *(const half8*)(p + a_pl);
                rA1b = *(const half8*)(p + a_pl + 8);
            } else { rA0a = rA0b = rA1a = rA1b = zero8; }
        } else if (AMODE == 1) {
            if (rg < M) {
                int c0 = n0 + acb;
                int k0 = c0 / Fi, fi0 = c0 - k0 * Fi;
                int v0 = idx[(u64)rg * 9 + k0];
                rA0a = *(const half8*)(Aw + (u64)b * a_bs + (u64)v0 * Fi + fi0);
                int c1 = c0 + 8;
                int k1 = c1 / Fi, fi1 = c1 - k1 * Fi;
                int v1 = (k1 == k0) ? v0 : idx[(u64)rg * 9 + k1];
                rA0b = *(const half8*)(Aw + (u64)b * a_bs + (u64)v1 * Fi + fi1);
            } else { rA0a = rA0b = zero8; }
        } else if (AMODE == 3) {
            if (rg < M) {
                const _Float16* p = Aw + (u64)rg * Np + n0 + acb;
                rA0a = *(const half8*)p;
                rA0b = *(const half8*)(p + 8);
            } else { rA0a = rA0b = zero8; }
        }
    };
    auto loadB = [&](int ks) {
        int n0 = ks * BK;
        if (BDUAL) {
            const _Float16* p = Bw + (u64)(f0 + br) * Np + n0 + bcb;
            rB0 = *(const half8*)p;
            rB1 = *(const half8*)(p + b_pl);
        } else {
            rB0 = *(const half8*)(Bw + (u64)b * b_bs + (u64)(f0 + br) * Np + n0 + bcb);
        }
    };
    auto store = [&]() {
        if (AMODE == 2) {
            int rg = m0 + ar;
            #pragma unroll
            for (int q = 0; q < 16; ++q) {
                int n = acb + q;
                _Float16 val = (_Float16)0;
                if (rg < M && n < Nreal) {
                    int k = n / Fi, fi = n - k * Fi;
                    int v = idx[(u64)rg * 9 + k];
                    val = Aw[(u64)b * a_bs + (u64)v * Fi + fi];
                }
                sA[0][ar][n] = val;
            }
        } else {
            *(half8*)&sA[0][ar][acb] = rA0a;
            *(half8*)&sA[0][ar][acb + 8] = rA0b;
            if constexpr (ADUAL) {
                *(half8*)&sA[APL - 1][ar][acb] = rA1a;
                *(half8*)&sA[APL - 1][ar][acb + 8] = rA1b;
            }
        }
        *(half8*)&sB[0][br][bcb] = rB0;
        if constexpr (BDUAL) *(half8*)&sB[BPL - 1][br][bcb] = rB1;
    };

    loadA(0); loadB(0);
    for (int ks = 0; ks < nk; ++ks) {
        __syncthreads();
        store();
        __syncthreads();
        if (ks + 1 < nk) { loadA(ks + 1); loadB(ks + 1); }

        half8 a0[4], a1[4], b0[2], b1[2];
        #pragma unroll
        for (int i = 0; i < 4; ++i) {
            a0[i] = *(const half8*)&sA[0][wm * 64 + i * 16 + lm][lg * 8];
            if constexpr (ADUAL) a1[i] = *(const half8*)&sA[APL - 1][wm * 64 + i * 16 + lm][lg * 8];
        }
        #pragma unroll
        for (int j = 0; j < 2; ++j) {
            b0[j] = *(const half8*)&sB[0][wf * 32 + j * 16 + lm][lg * 8];
            if constexpr (BDUAL) b1[j] = *(const half8*)&sB[BPL - 1][wf * 32 + j * 16 + lm][lg * 8];
        }
        #pragma unroll
        for (int i = 0; i < 4; ++i)
            #pragma unroll
            for (int j = 0; j < 2; ++j) {
                acc[i][j] = __builtin_amdgcn_mfma_f32_16x16x32_f16(a0[i], b0[j], acc[i][j], 0, 0, 0);
                if constexpr (ADUAL)
                    acc[i][j] = __builtin_amdgcn_mfma_f32_16x16x32_f16(a1[i], b0[j], acc[i][j], 0, 0, 0);
                else
                    acc[i][j] = __builtin_amdgcn_mfma_f32_16x16x32_f16(a0[i], b1[j], acc[i][j], 0, 0, 0);
            }
    }

    // epilogue
    #pragma unroll
    for (int j = 0; j < 2; ++j) {
        int fl = f0 + wf * 32 + j * 16 + lm;
        float bv = 0.f;
        if (bias != nullptr && fl < F) bv = bias[fl];
        #pragma unroll
        for (int i = 0; i < 4; ++i) {
            #pragma unroll
            for (int r = 0; r < 4; ++r) {
                int m = m0 + wm * 64 + i * 16 + lg * 4 + r;
                float v = acc[i][j][r] + bv;
                if (flags & 1) v = (v > 0.f) ? v : expm1f(v);
                if (EPI == EPI_NAT) {
                    if (m < M && fl < F)
                        ((_Float16*)Cp)[(u64)b * c_bs + (u64)m * F + fl] = (_Float16)v;
                } else if (EPI == EPI_TR) {
                    if (m < Mp_out && fl < F) {
                        float o = (m < M && !((flags & 2) && m == M - 1)) ? v : 0.f;
                        ((_Float16*)Cp)[(u64)b * c_bs + (u64)fl * Mp_out + m] = (_Float16)o;
                    }
                } else if (EPI == EPI_FCD) {
                    if (m < M && fl < F) {
                        int fi = fl & 255, nn = fl >> 8;
                        ((_Float16*)Cp)[(u64)m * 8192 + fi * 32 + nn] = (_Float16)v;
                    }
                } else { // EPI_OUT
                    if (m < M && fl < 3) {
                        float o = ((flags & 2) && m == M - 1) ? 0.f : v;
                        ((float*)Cp)[((u64)b * M + m) * 3 + fl] = o;
                    }
                }
            }
        }
    }
}

// ---- conversion kernels (run every call; weights -> fp16 hi/lo planes) ----
__global__ void cvt_dual(const float* __restrict__ src, _Float16* __restrict__ dst,
                         int N, int Np, size_t pl)
{
    int n = blockIdx.x * 256 + threadIdx.x;
    if (n >= Np) return;
    size_t m = blockIdx.y;
    float v = (n < N) ? src[m * N + n] : 0.f;
    _Float16 h = (_Float16)v;
    dst[m * Np + n] = h;
    dst[m * Np + n + pl] = (_Float16)(v - (float)h);
}

__global__ void cvt_dualT(const float* __restrict__ src, _Float16* __restrict__ dst,
                          int N, int F, int Np, size_t pl)
{
    int n = blockIdx.x * 256 + threadIdx.x;
    if (n >= Np) return;
    int f = blockIdx.y;
    float v = (n < N && f < F) ? src[(size_t)n * F + f] : 0.f;
    _Float16 h = (_Float16)v;
    size_t o = (size_t)f * Np + n;
    dst[o] = h;
    dst[o + pl] = (_Float16)(v - (float)h);
}

__global__ void cvt_single(const float* __restrict__ src, _Float16* __restrict__ dst, size_t n)
{
    size_t i = (size_t)blockIdx.x * 256 + threadIdx.x;
    if (i < n) dst[i] = (_Float16)src[i];
}

extern "C" void kernel_launch(void* const* d_in, const int* in_sizes, int n_in,
                              void* d_out, int out_size, void* d_ws, size_t ws_size,
                              hipStream_t stream)
{
    const float* x  = (const float*)d_in[0];
    const int* s0 = (const int*)d_in[1];
    const int* s1 = (const int*)d_in[2];
    const int* s2 = (const int*)d_in[3];
    const int* s3 = (const int*)d_in[4];
    const float* D0 = (const float*)d_in[5];
    const float* U0_ = (const float*)d_in[6];
    const float* D1 = (const float*)d_in[7];
    const float* U1_ = (const float*)d_in[8];
    const float* D2 = (const float*)d_in[9];
    const float* U2_ = (const float*)d_in[10];
    const float* D3 = (const float*)d_in[11];
    const float* U3_ = (const float*)d_in[12];
    const float* We0 = (const float*)d_in[13]; const float* be0 = (const float*)d_in[14];
    const float* We1 = (const float*)d_in[15]; const float* be1 = (const float*)d_in[16];
    const float* We2 = (const float*)d_in[17]; const float* be2 = (const float*)d_in[18];
    const float* We3 = (const float*)d_in[19]; const float* be3 = (const float*)d_in[20];
    const float* fceW = (const float*)d_in[21]; const float* fceb = (const float*)d_in[22];
    const float* fcdW = (const float*)d_in[23]; const float* fcdb = (const float*)d_in[24];
    const float* Wd0 = (const float*)d_in[25]; const float* bd0 = (const float*)d_in[26];
    const float* Wd1 = (const float*)d_in[27]; const float* bd1 = (const float*)d_in[28];
    const float* Wd2 = (const float*)d_in[29]; const float* bd2 = (const float*)d_in[30];
    const float* Wd3 = (const float*)d_in[31]; const float* bd3 = (const float*)d_in[32];

    _Float16* W = (_Float16*)d_ws;
    size_t off = 0;
    auto alloc = [&](size_t e) { size_t o = off; off += (e + 255) & ~(size_t)255; return o; };

    const size_t oBufA = alloc((size_t)64 * 64 * 5024);   // transposed act planes [b][f][Mp]
    const size_t oBufB = alloc((size_t)64 * 5024 * 64);   // natural act planes  [b][v][f]
    const size_t oZ    = alloc((size_t)64 * 256);
    const size_t oFcd  = alloc((size_t)64 * 256 * 32);
    const size_t oD0 = alloc((size_t)2 * 1257 * 5024);
    const size_t oU0 = alloc((size_t)2 * 5024 * 1280);
    const size_t oD1 = alloc((size_t)2 * 315 * 1280);
    const size_t oU1 = alloc((size_t)2 * 1257 * 320);
    const size_t oD2 = alloc((size_t)2 * 80 * 320);
    const size_t oU2 = alloc((size_t)2 * 315 * 96);
    const size_t oD3 = alloc((size_t)2 * 21 * 96);
    const size_t oU3 = alloc((size_t)2 * 80 * 32);
    const size_t oWe0 = alloc((size_t)2 * 64 * 32);
    const size_t oWe1 = alloc((size_t)2 * 64 * 576);
    const size_t oWe2 = alloc((size_t)2 * 128 * 576);
    const size_t oWe3 = alloc((size_t)2 * 256 * 1152);
    const size_t oFce = alloc((size_t)2 * 256 * 5376);
    const size_t oFcW = alloc((size_t)2 * 5376 * 256);
    const size_t oWd0 = alloc((size_t)2 * 128 * 2304);
    const size_t oWd1 = alloc((size_t)2 * 64 * 1152);
    const size_t oWd2 = alloc((size_t)2 * 64 * 576);
    const size_t oWd3 = alloc((size_t)2 * 64 * 576);
    const size_t oX   = alloc((size_t)64 * 5024 * 3);

    // ---- conversions ----
    {
        size_t n = (size_t)64 * 5024 * 3;
        cvt_single<<<dim3((unsigned)((n + 255) / 256)), 256, 0, stream>>>(x, W + oX, n);
    }
    auto cdual = [&](const float* src, size_t o, int M_, int N_, int Np_) {
        cvt_dual<<<dim3((Np_ + 255) / 256, M_), 256, 0, stream>>>(src, W + o, N_, Np_, (size_t)M_ * Np_);
    };
    auto cdT = [&](const float* src, size_t o, int N_, int F_, int Np_, int Fp_) {
        cvt_dualT<<<dim3((Np_ + 255) / 256, Fp_), 256, 0, stream>>>(src, W + o, N_, F_, Np_, (size_t)Fp_ * Np_);
    };
    cdual(D0, oD0, 1257, 5024, 5024);
    cdual(U0_, oU0, 5024, 1257, 1280);
    cdual(D1, oD1, 315, 1257, 1280);
    cdual(U1_, oU1, 1257, 315, 320);
    cdual(D2, oD2, 80, 315, 320);
    cdual(U2_, oU2, 315, 80, 96);
    cdual(D3, oD3, 21, 80, 96);
    cdual(U3_, oU3, 80, 21, 32);
    cdT(We0, oWe0, 27, 64, 32, 64);
    cdT(We1, oWe1, 576, 64, 576, 64);
    cdT(We2, oWe2, 576, 128, 576, 128);
    cdT(We3, oWe3, 1152, 256, 1152, 256);
    cdT(fceW, oFce, 5376, 256, 5376, 256);
    cdT(fcdW, oFcW, 256, 5376, 256, 5376);
    cdT(Wd0, oWd0, 2304, 128, 2304, 128);
    cdT(Wd1, oWd1, 1152, 64, 1152, 64);
    cdT(Wd2, oWd2, 576, 64, 576, 64);
    cdT(Wd3, oWd3, 576, 3, 576, 64);
    hipMemsetAsync(W + oFcd, 0, (size_t)64 * 256 * 32 * sizeof(_Float16), stream);

    #define GEMM(AM, EP, gx, gy, gz, Aw_, abs_, apl_, idx_, Fi_, Nr_, Bw_, bbs_, bpl_, bias_, Cp_, cbs_, Mp_, M_, Np_, F_, fl_) \
        gemm_k<AM, EP><<<dim3(gx, gy, gz), 256, 0, stream>>>(Aw_, abs_, apl_, idx_, Fi_, Nr_, Bw_, bbs_, bpl_, bias_, Cp_, cbs_, Mp_, M_, Np_, F_, fl_)

    // ---- encoder ----
    GEMM(2, EPI_TR, 1, 40, 64, W + oX, (u64)5024 * 3, 0, s0, 3, 27,
         W + oWe0, 0, (u64)64 * 32, be0, W + oBufA, (u64)64 * 5024, 5024, 5024, 32, 64, 3);
    GEMM(0, EPI_NAT, 1, 10, 64, W + oD0, 0, (u64)1257 * 5024, nullptr, 0, 0,
         W + oBufA, (u64)64 * 5024, 0, nullptr, W + oBufB, (u64)1257 * 64, 0, 1257, 5024, 64, 0);
    GEMM(1, EPI_TR, 1, 10, 64, W + oBufB, (u64)1257 * 64, 0, s1, 64, 576,
         W + oWe1, 0, (u64)64 * 576, be1, W + oBufA, (u64)64 * 1280, 1280, 1257, 576, 64, 3);
    GEMM(0, EPI_NAT, 1, 3, 64, W + oD1, 0, (u64)315 * 1280, nullptr, 0, 0,
         W + oBufA, (u64)64 * 1280, 0, nullptr, W + oBufB, (u64)315 * 64, 0, 315, 1280, 64, 0);
    GEMM(1, EPI_TR, 2, 3, 64, W + oBufB, (u64)315 * 64, 0, s2, 64, 576,
         W + oWe2, 0, (u64)128 * 576, be2, W + oBufA, (u64)128 * 320, 320, 315, 576, 128, 3);
    GEMM(0, EPI_NAT, 2, 1, 64, W + oD2, 0, (u64)80 * 320, nullptr, 0, 0,
         W + oBufA, (u64)128 * 320, 0, nullptr, W + oBufB, (u64)80 * 128, 0, 80, 320, 128, 0);
    GEMM(1, EPI_TR, 4, 1, 64, W + oBufB, (u64)80 * 128, 0, s3, 128, 1152,
         W + oWe3, 0, (u64)256 * 1152, be3, W + oBufA, (u64)256 * 96, 96, 80, 1152, 256, 3);
    GEMM(0, EPI_NAT, 4, 1, 64, W + oD3, 0, (u64)21 * 96, nullptr, 0, 0,
         W + oBufA, (u64)256 * 96, 0, nullptr, W + oBufB, (u64)21 * 256, 0, 21, 96, 256, 0);
    // ---- bottleneck ----
    GEMM(3, EPI_NAT, 4, 1, 1, W + oBufB, 0, 0, nullptr, 0, 0,
         W + oFce, 0, (u64)256 * 5376, fceb, W + oZ, (u64)64 * 256, 0, 64, 5376, 256, 0);
    GEMM(3, EPI_FCD, 84, 1, 1, W + oZ, 0, 0, nullptr, 0, 0,
         W + oFcW, 0, (u64)5376 * 256, fcdb, W + oFcd, 0, 0, 64, 256, 5376, 0);
    // ---- decoder ----
    GEMM(0, EPI_NAT, 4, 1, 64, W + oU3, 0, (u64)80 * 32, nullptr, 0, 0,
         W + oFcd, (u64)256 * 32, 0, nullptr, W + oBufB, (u64)80 * 256, 0, 80, 32, 256, 0);
    GEMM(1, EPI_TR, 2, 1, 64, W + oBufB, (u64)80 * 256, 0, s3, 256, 2304,
         W + oWd0, 0, (u64)128 * 2304, bd0, W + oBufA, (u64)128 * 96, 96, 80, 2304, 128, 3);
    GEMM(0, EPI_NAT, 2, 3, 64, W + oU2, 0, (u64)315 * 96, nullptr, 0, 0,
         W + oBufA, (u64)128 * 96, 0, nullptr, W + oBufB, (u64)315 * 128, 0, 315, 96, 128, 0);
    GEMM(1, EPI_TR, 1, 3, 64, W + oBufB, (u64)315 * 128, 0, s2, 128, 1152,
         W + oWd1, 0, (u64)64 * 1152, bd1, W + oBufA, (u64)64 * 320, 320, 315, 1152, 64, 3);
    GEMM(0, EPI_NAT, 1, 10, 64, W + oU1, 0, (u64)1257 * 320, nullptr, 0, 0,
         W + oBufA, (u64)64 * 320, 0, nullptr, W + oBufB, (u64)1257 * 64, 0, 1257, 320, 64, 0);
    GEMM(1, EPI_TR, 1, 10, 64, W + oBufB, (u64)1257 * 64, 0, s1, 64, 576,
         W + oWd2, 0, (u64)64 * 576, bd2, W + oBufA, (u64)64 * 1280, 1280, 1257, 576, 64, 3);
    GEMM(0, EPI_NAT, 1, 40, 64, W + oU0, 0, (u64)5024 * 1280, nullptr, 0, 0,
         W + oBufA, (u64)64 * 1280, 0, nullptr, W + oBufB, (u64)5024 * 64, 0, 5024, 1280, 64, 0);
    GEMM(1, EPI_OUT, 1, 40, 64, W + oBufB, (u64)5024 * 64, 0, s0, 64, 576,
         W + oWd3, 0, (u64)64 * 576, bd3, d_out, 0, 0, 5024, 576, 3, 2);
    #undef GEMM
}

// Round 4
// 852.971 us; speedup vs baseline: 5.6945x; 1.9140x over previous
//
#include <hip/hip_runtime.h>
#include <math.h>

typedef __attribute__((ext_vector_type(8))) _Float16 half8;
typedef __attribute__((ext_vector_type(4))) float f32x4;

#define BK 32
#define SK 40

#define EPI_NAT 0
#define EPI_TR  1
#define EPI_FCD 2
#define EPI_OUT 3

typedef unsigned long long u64;

// AMODE: 0 pool   (A single [M][Np]; B = act_T single, rows = global (b,f))
//        1 sconv  (A gather from act_V via idx, grid.z = batch; B dual weights)
//        2 sconv0 (A scalar gather, Fi=3; B dual weights)
//        3 fc     (A plain [M][Np] fp16; B dual weights)
//        4 fc-e   (A from act_V [v][(b,f)], rows = batch; B dual weights)
//        5 sconv rows-folded (rows = v*64+b; B dual weights)  [Wd3]
template<int AMODE, int EPI, int TBM, int TBF, int WM, int WF>
__global__ __launch_bounds__(256) void gemm_k(
    const _Float16* __restrict__ Aw, u64 a_rs,
    const int* __restrict__ idx, int FiLog, int Nreal,
    const _Float16* __restrict__ Bw, u64 b_pl,
    const float* __restrict__ bias,
    void* __restrict__ Cp, u64 c_rs, int Mp_out,
    int M, int Np, int F, int flags)   // flags: bit0 ELU, bit1 zeroLast
{
    constexpr bool BDUAL = (AMODE != 0);
    constexpr int BPL = BDUAL ? 2 : 1;
    constexpr int FM = TBM / WM / 16;
    constexpr int FF = TBF / WF / 16;

    __shared__ _Float16 sA[TBM][SK];
    __shared__ _Float16 sB[BPL][TBF][SK];

    const int t = threadIdx.x;
    const int b = blockIdx.z;
    const int m0 = blockIdx.y * TBM;
    const int f0 = blockIdx.x * TBF;
    const int lane = t & 63;
    const int wid = t >> 6;
    const int wm = wid / WF;
    const int wf = wid % WF;
    const int lm = lane & 15;
    const int lg = lane >> 4;
    const int nk = Np / BK;
    const int Fi = 1 << FiLog;

    f32x4 acc[FM][FF];
    #pragma unroll
    for (int i = 0; i < FM; ++i)
        #pragma unroll
        for (int j = 0; j < FF; ++j)
            acc[i][j] = (f32x4)0.0f;

    // staging maps (full BM/BF x 32 coverage)
    constexpr int ACH = (TBM == 128) ? 2 : 1;
    int ar, acb;
    if constexpr (TBM == 128) { ar = t >> 1; acb = (t & 1) * 16; }
    else                      { ar = t >> 2; acb = (t & 3) * 8; }

    constexpr int BCH = (TBF == 128) ? 2 : 1;
    int br, bcb;
    bool bact = true;
    if constexpr (TBF == 128)      { br = t >> 1;        bcb = (t & 1) * 16; }
    else if constexpr (TBF == 64)  { br = t >> 2;        bcb = (t & 3) * 8; }
    else                           { br = (t & 63) >> 2; bcb = (t & 3) * 8; bact = (t < 64); }

    half8 zero8 = {(_Float16)0,(_Float16)0,(_Float16)0,(_Float16)0,
                   (_Float16)0,(_Float16)0,(_Float16)0,(_Float16)0};
    half8 rA[2] = {zero8, zero8};
    half8 rB0[2] = {zero8, zero8}, rB1[2] = {zero8, zero8};

    auto loadA = [&](int ks) {
        if constexpr (AMODE == 2) return;
        int rg = m0 + ar;
        #pragma unroll
        for (int c = 0; c < ACH; ++c) {
            int col = ks * BK + acb + c * 8;
            rA[c] = zero8;
            if constexpr (AMODE == 0 || AMODE == 3) {
                if (rg < M) rA[c] = *(const half8*)(Aw + (u64)rg * Np + col);
            } else if constexpr (AMODE == 1) {
                if (rg < M) {
                    int k = col >> FiLog, fi = col & (Fi - 1);
                    int vs = idx[rg * 9 + k];
                    rA[c] = *(const half8*)(Aw + (u64)vs * a_rs + b * Fi + fi);
                }
            } else if constexpr (AMODE == 4) {
                if (rg < M) {
                    int k = col >> FiLog, fi = col & (Fi - 1);
                    rA[c] = *(const half8*)(Aw + (u64)k * a_rs + rg * Fi + fi);
                }
            } else if constexpr (AMODE == 5) {
                if (rg < M) {
                    int vo = rg >> 6, bb = rg & 63;
                    int k = col >> FiLog, fi = col & (Fi - 1);
                    int vs = idx[vo * 9 + k];
                    rA[c] = *(const half8*)(Aw + (u64)vs * a_rs + bb * Fi + fi);
                }
            }
        }
    };
    auto loadB = [&](int ks) {
        if (!bact) return;
        #pragma unroll
        for (int c = 0; c < BCH; ++c) {
            int col = ks * BK + bcb + c * 8;
            const _Float16* p = Bw + (u64)(f0 + br) * Np + col;
            rB0[c] = *(const half8*)p;
            if constexpr (BDUAL) rB1[c] = *(const half8*)(p + b_pl);
        }
    };
    auto store = [&]() {
        if constexpr (AMODE == 2) {
            int rg = m0 + ar;
            #pragma unroll
            for (int q = 0; q < 16; ++q) {
                int n = acb + q;   // nk==1 for AMODE 2
                _Float16 val = (_Float16)0.f;
                if (rg < M && n < Nreal) {
                    int k = n / 3, fi = n - k * 3;
                    int vs = idx[rg * 9 + k];
                    val = Aw[(u64)vs * a_rs + b * 3 + fi];
                }
                sA[ar][n] = val;
            }
        } else {
            #pragma unroll
            for (int c = 0; c < ACH; ++c)
                *(half8*)&sA[ar][acb + c * 8] = rA[c];
        }
        if (bact) {
            #pragma unroll
            for (int c = 0; c < BCH; ++c) {
                *(half8*)&sB[0][br][bcb + c * 8] = rB0[c];
                if constexpr (BDUAL) *(half8*)&sB[1][br][bcb + c * 8] = rB1[c];
            }
        }
    };

    loadA(0); loadB(0);
    for (int ks = 0; ks < nk; ++ks) {
        __syncthreads();
        store();
        __syncthreads();
        if (ks + 1 < nk) { loadA(ks + 1); loadB(ks + 1); }

        half8 af[FM], bf0[FF], bf1[FF];
        #pragma unroll
        for (int i = 0; i < FM; ++i)
            af[i] = *(const half8*)&sA[wm * (FM * 16) + i * 16 + lm][lg * 8];
        #pragma unroll
        for (int j = 0; j < FF; ++j) {
            bf0[j] = *(const half8*)&sB[0][wf * (FF * 16) + j * 16 + lm][lg * 8];
            if constexpr (BDUAL)
                bf1[j] = *(const half8*)&sB[1][wf * (FF * 16) + j * 16 + lm][lg * 8];
        }
        #pragma unroll
        for (int i = 0; i < FM; ++i)
            #pragma unroll
            for (int j = 0; j < FF; ++j) {
                acc[i][j] = __builtin_amdgcn_mfma_f32_16x16x32_f16(af[i], bf0[j], acc[i][j], 0, 0, 0);
                if constexpr (BDUAL)
                    acc[i][j] = __builtin_amdgcn_mfma_f32_16x16x32_f16(af[i], bf1[j], acc[i][j], 0, 0, 0);
            }
    }

    #pragma unroll
    for (int j = 0; j < FF; ++j) {
        int fl = f0 + wf * (FF * 16) + j * 16 + lm;
        float bv = 0.f;
        if (bias != nullptr && fl < F) bv = bias[fl];
        #pragma unroll
        for (int i = 0; i < FM; ++i) {
            #pragma unroll
            for (int r = 0; r < 4; ++r) {
                int m = m0 + wm * (FM * 16) + i * 16 + lg * 4 + r;
                float v = acc[i][j][r] + bv;
                if (flags & 1) v = (v > 0.f) ? v : expm1f(v);
                if constexpr (EPI == EPI_NAT) {
                    if (m < M && fl < F)
                        ((_Float16*)Cp)[(u64)m * c_rs + fl] = (_Float16)v;
                } else if constexpr (EPI == EPI_TR) {
                    if (m < Mp_out && fl < F) {
                        float o = (m < M && !((flags & 2) && m == M - 1)) ? v : 0.f;
                        ((_Float16*)Cp)[(u64)b * c_rs + (u64)fl * Mp_out + m] = (_Float16)o;
                    }
                } else if constexpr (EPI == EPI_FCD) {
                    if (m < M && fl < F)
                        ((_Float16*)Cp)[((u64)m * 256 + (fl & 255)) * 32 + (fl >> 8)] = (_Float16)v;
                } else { // EPI_OUT (rows folded: m = v*64+b)
                    if (m < M && fl < F) {
                        int vo = m >> 6, bb = m & 63;
                        float o = ((flags & 2) && vo == Mp_out - 1) ? 0.f : v;
                        ((float*)Cp)[((u64)bb * Mp_out + vo) * 3 + fl] = o;
                    }
                }
            }
        }
    }
}

// ---- conversion kernels ----
__global__ void cvt_pool(const float* __restrict__ src, _Float16* __restrict__ dst,
                         int N, int Np)
{
    int n = blockIdx.x * 256 + threadIdx.x;
    if (n >= Np) return;
    u64 m = blockIdx.y;
    dst[m * Np + n] = (n < N) ? (_Float16)src[m * N + n] : (_Float16)0.f;
}

__global__ void cvt_dualT(const float* __restrict__ src, _Float16* __restrict__ dst,
                          int N, int F, int Np, u64 pl)
{
    int n = blockIdx.x * 256 + threadIdx.x;
    if (n >= Np) return;
    int f = blockIdx.y;
    float v = (n < N && f < F) ? src[(u64)n * F + f] : 0.f;
    _Float16 h = (_Float16)v;
    u64 o = (u64)f * Np + n;
    dst[o] = h;
    dst[o + pl] = (_Float16)(v - (float)h);
}

__global__ void cvt_x(const float* __restrict__ src, _Float16* __restrict__ dst)
{
    int i = blockIdx.x * 256 + threadIdx.x;
    if (i >= 64 * 5024 * 3) return;
    int v = i / 192;
    int r = i - v * 192;
    int b = r / 3, c = r - b * 3;
    dst[i] = (_Float16)src[((u64)b * 5024 + v) * 3 + c];
}

extern "C" void kernel_launch(void* const* d_in, const int* in_sizes, int n_in,
                              void* d_out, int out_size, void* d_ws, size_t ws_size,
                              hipStream_t stream)
{
    const float* x  = (const float*)d_in[0];
    const int* s0 = (const int*)d_in[1];
    const int* s1 = (const int*)d_in[2];
    const int* s2 = (const int*)d_in[3];
    const int* s3 = (const int*)d_in[4];
    const float* D0 = (const float*)d_in[5];
    const float* U0_ = (const float*)d_in[6];
    const float* D1 = (const float*)d_in[7];
    const float* U1_ = (const float*)d_in[8];
    const float* D2 = (const float*)d_in[9];
    const float* U2_ = (const float*)d_in[10];
    const float* D3 = (const float*)d_in[11];
    const float* U3_ = (const float*)d_in[12];
    const float* We0 = (const float*)d_in[13]; const float* be0 = (const float*)d_in[14];
    const float* We1 = (const float*)d_in[15]; const float* be1 = (const float*)d_in[16];
    const float* We2 = (const float*)d_in[17]; const float* be2 = (const float*)d_in[18];
    const float* We3 = (const float*)d_in[19]; const float* be3 = (const float*)d_in[20];
    const float* fceW = (const float*)d_in[21]; const float* fceb = (const float*)d_in[22];
    const float* fcdW = (const float*)d_in[23]; const float* fcdb = (const float*)d_in[24];
    const float* Wd0 = (const float*)d_in[25]; const float* bd0 = (const float*)d_in[26];
    const float* Wd1 = (const float*)d_in[27]; const float* bd1 = (const float*)d_in[28];
    const float* Wd2 = (const float*)d_in[29]; const float* bd2 = (const float*)d_in[30];
    const float* Wd3 = (const float*)d_in[31]; const float* bd3 = (const float*)d_in[32];

    _Float16* W = (_Float16*)d_ws;
    size_t off = 0;
    auto alloc = [&](size_t e) { size_t o = off; off += (e + 255) & ~(size_t)255; return o; };

    const size_t oActV = alloc((size_t)5024 * 4096);
    const size_t oActT = alloc((size_t)4096 * 5024);
    const size_t oZ    = alloc((size_t)64 * 256);
    const size_t oU3in = alloc((size_t)16384 * 32);
    const size_t oXp   = alloc((size_t)5024 * 192);
    const size_t oD0 = alloc((size_t)1257 * 5024);
    const size_t oU0 = alloc((size_t)5024 * 1280);
    const size_t oD1 = alloc((size_t)315 * 1280);
    const size_t oU1 = alloc((size_t)1257 * 320);
    const size_t oD2 = alloc((size_t)80 * 320);
    const size_t oU2 = alloc((size_t)315 * 96);
    const size_t oD3 = alloc((size_t)21 * 96);
    const size_t oU3 = alloc((size_t)80 * 32);
    const size_t oWe0 = alloc((size_t)2 * 64 * 32);
    const size_t oWe1 = alloc((size_t)2 * 64 * 576);
    const size_t oWe2 = alloc((size_t)2 * 128 * 576);
    const size_t oWe3 = alloc((size_t)2 * 256 * 1152);
    const size_t oFce = alloc((size_t)2 * 256 * 5376);
    const size_t oFcW = alloc((size_t)2 * 5376 * 256);
    const size_t oWd0 = alloc((size_t)2 * 128 * 2304);
    const size_t oWd1 = alloc((size_t)2 * 64 * 1152);
    const size_t oWd2 = alloc((size_t)2 * 64 * 576);
    const size_t oWd3 = alloc((size_t)2 * 16 * 576);

    // ---- conversions ----
    cvt_x<<<dim3((64 * 5024 * 3 + 255) / 256), 256, 0, stream>>>(x, W + oXp);
    auto cpool = [&](const float* src, size_t o, int M_, int N_, int Np_) {
        cvt_pool<<<dim3((Np_ + 255) / 256, M_), 256, 0, stream>>>(src, W + o, N_, Np_);
    };
    auto cdT = [&](const float* src, size_t o, int N_, int F_, int Np_, int Fp_) {
        cvt_dualT<<<dim3((Np_ + 255) / 256, Fp_), 256, 0, stream>>>(src, W + o, N_, F_, Np_, (u64)Fp_ * Np_);
    };
    cpool(D0, oD0, 1257, 5024, 5024);
    cpool(U0_, oU0, 5024, 1257, 1280);
    cpool(D1, oD1, 315, 1257, 1280);
    cpool(U1_, oU1, 1257, 315, 320);
    cpool(D2, oD2, 80, 315, 320);
    cpool(U2_, oU2, 315, 80, 96);
    cpool(D3, oD3, 21, 80, 96);
    cpool(U3_, oU3, 80, 21, 32);
    cdT(We0, oWe0, 27, 64, 32, 64);
    cdT(We1, oWe1, 576, 64, 576, 64);
    cdT(We2, oWe2, 576, 128, 576, 128);
    cdT(We3, oWe3, 1152, 256, 1152, 256);
    cdT(fceW, oFce, 5376, 256, 5376, 256);
    cdT(fcdW, oFcW, 256, 5376, 256, 5376);
    cdT(Wd0, oWd0, 2304, 128, 2304, 128);
    cdT(Wd1, oWd1, 1152, 64, 1152, 64);
    cdT(Wd2, oWd2, 576, 64, 576, 64);
    cdT(Wd3, oWd3, 576, 3, 576, 16);

    #define GEMM(AM, EP, BM_, BF_, WM_, WF_, gx, gy, gz, Aw_, ars_, idx_, FiL_, Nr_, Bw_, bpl_, bias_, Cp_, crs_, Mp_, M_, Np_, F_, fl_) \
        gemm_k<AM, EP, BM_, BF_, WM_, WF_><<<dim3(gx, gy, gz), 256, 0, stream>>>( \
            Aw_, ars_, idx_, FiL_, Nr_, Bw_, bpl_, bias_, Cp_, crs_, Mp_, M_, Np_, F_, fl_)

    // ---- encoder ----
    GEMM(2, EPI_TR, 128, 64, 2, 2, 1, 40, 64, W + oXp, 192, s0, 0, 27,
         W + oWe0, (u64)64 * 32, be0, W + oActT, (u64)64 * 5024, 5024, 5024, 32, 64, 3);
    GEMM(0, EPI_NAT, 128, 128, 2, 2, 32, 10, 1, W + oD0, 0, nullptr, 0, 0,
         W + oActT, 0, nullptr, W + oActV, 4096, 0, 1257, 5024, 4096, 0);
    GEMM(1, EPI_TR, 128, 64, 2, 2, 1, 10, 64, W + oActV, 4096, s1, 6, 0,
         W + oWe1, (u64)64 * 576, be1, W + oActT, (u64)64 * 1280, 1280, 1257, 576, 64, 3);
    GEMM(0, EPI_NAT, 128, 128, 2, 2, 32, 3, 1, W + oD1, 0, nullptr, 0, 0,
         W + oActT, 0, nullptr, W + oActV, 4096, 0, 315, 1280, 4096, 0);
    GEMM(1, EPI_TR, 128, 64, 2, 2, 2, 3, 64, W + oActV, 4096, s2, 6, 0,
         W + oWe2, (u64)128 * 576, be2, W + oActT, (u64)128 * 320, 320, 315, 576, 128, 3);
    GEMM(0, EPI_NAT, 128, 128, 2, 2, 64, 1, 1, W + oD2, 0, nullptr, 0, 0,
         W + oActT, 0, nullptr, W + oActV, 8192, 0, 80, 320, 8192, 0);
    GEMM(1, EPI_TR, 128, 64, 2, 2, 4, 1, 64, W + oActV, 8192, s3, 7, 0,
         W + oWe3, (u64)256 * 1152, be3, W + oActT, (u64)256 * 96, 96, 80, 1152, 256, 3);
    GEMM(0, EPI_NAT, 128, 128, 2, 2, 128, 1, 1, W + oD3, 0, nullptr, 0, 0,
         W + oActT, 0, nullptr, W + oActV, 16384, 0, 21, 96, 16384, 0);
    // ---- bottleneck ----
    GEMM(4, EPI_NAT, 64, 64, 2, 2, 4, 1, 1, W + oActV, 16384, nullptr, 8, 0,
         W + oFce, (u64)256 * 5376, fceb, W + oZ, 256, 0, 64, 5376, 256, 0);
    hipMemsetAsync(W + oU3in, 0, (size_t)16384 * 32 * sizeof(_Float16), stream);
    GEMM(3, EPI_FCD, 64, 64, 2, 2, 84, 1, 1, W + oZ, 0, nullptr, 0, 0,
         W + oFcW, (u64)5376 * 256, fcdb, W + oU3in, 0, 0, 64, 256, 5376, 0);
    // ---- decoder ----
    GEMM(0, EPI_NAT, 128, 128, 2, 2, 128, 1, 1, W + oU3, 0, nullptr, 0, 0,
         W + oU3in, 0, nullptr, W + oActV, 16384, 0, 80, 32, 16384, 0);
    GEMM(1, EPI_TR, 128, 64, 2, 2, 2, 1, 64, W + oActV, 16384, s3, 8, 0,
         W + oWd0, (u64)128 * 2304, bd0, W + oActT, (u64)128 * 96, 96, 80, 2304, 128, 3);
    GEMM(0, EPI_NAT, 128, 128, 2, 2, 64, 3, 1, W + oU2, 0, nullptr, 0, 0,
         W + oActT, 0, nullptr, W + oActV, 8192, 0, 315, 96, 8192, 0);
    GEMM(1, EPI_TR, 128, 64, 2, 2, 1, 3, 64, W + oActV, 8192, s2, 7, 0,
         W + oWd1, (u64)64 * 1152, bd1, W + oActT, (u64)64 * 320, 320, 315, 1152, 64, 3);
    GEMM(0, EPI_NAT, 128, 128, 2, 2, 32, 10, 1, W + oU1, 0, nullptr, 0, 0,
         W + oActT, 0, nullptr, W + oActV, 4096, 0, 1257, 320, 4096, 0);
    GEMM(1, EPI_TR, 128, 64, 2, 2, 1, 10, 64, W + oActV, 4096, s1, 6, 0,
         W + oWd2, (u64)64 * 576, bd2, W + oActT, (u64)64 * 1280, 1280, 1257, 576, 64, 3);
    GEMM(0, EPI_NAT, 128, 128, 2, 2, 32, 40, 1, W + oU0, 0, nullptr, 0, 0,
         W + oActT, 0, nullptr, W + oActV, 4096, 0, 5024, 1280, 4096, 0);
    GEMM(5, EPI_OUT, 128, 16, 4, 1, 1, 2512, 1, W + oActV, 4096, s0, 6, 0,
         W + oWd3, (u64)16 * 576, bd3, d_out, 0, 5024, 321536, 576, 3, 2);
    #undef GEMM
}

// Round 5
// 707.889 us; speedup vs baseline: 6.8616x; 1.2049x over previous
//
#include <hip/hip_runtime.h>
#include <math.h>

typedef __attribute__((ext_vector_type(8))) _Float16 half8;
typedef __attribute__((ext_vector_type(4))) float f32x4;
typedef unsigned long long u64;

#define BK 32

#define EPI_NAT  0
#define EPI_TR   1
#define EPI_FCD  2
#define EPI_OUT  3
#define EPI_PART 4

typedef const __attribute__((address_space(1))) void* gas1;
typedef __attribute__((address_space(3))) void* las3;

__device__ __forceinline__ void gl16(const void* g, void* l) {
    __builtin_amdgcn_global_load_lds((gas1)g, (las3)l, 16, 0, 0);
}

// AMODE: 0 pool  (A [M][Np] fp16; B = actT rows=(b,f))
//        1 sconv (A gathered from actV via idx, z=batch; B weightsT)
//        2 sconv0 (A scalar gather Fi=3, nk=1; B weightsT)
//        3 fc    (A plain [M][Np]; B weightsT)
//        4 fc-enc split-K (A from actV, rows=batch; z=K-split; B weightsT)
//        5 sconv rows-folded (rows = v*64+b; B weightsT)  [Wd3]
template<int AMODE, int EPI, int TBM, int TBF, int WM, int WF>
__global__ __launch_bounds__(256) void gemm_k(
    const _Float16* __restrict__ Aw, u64 a_rs,
    const int* __restrict__ idx, int FiLog,
    const _Float16* __restrict__ Bw,
    const float* __restrict__ bias,
    void* __restrict__ Cp, u64 c_rs, int Mp_out,
    int M, int Np, int F, int flags, int ksp)  // flags: bit0 ELU, bit1 zeroLast
{
    constexpr int FM = TBM / WM / 16;
    constexpr int FF = TBF / WF / 16;

    __shared__ _Float16 sA[2][TBM][BK];
    __shared__ _Float16 sB[2][TBF][BK];

    const int t  = threadIdx.x;
    const int b  = blockIdx.z;
    const int m0 = blockIdx.y * TBM;
    const int f0 = blockIdx.x * TBF;
    const int lane = t & 63;
    const int wid  = t >> 6;
    const int wm = wid / WF;
    const int wf = wid % WF;
    const int lm = lane & 15;
    const int lg = lane >> 4;
    const int Fi = 1 << FiLog;

    f32x4 acc[FM][FF];
    #pragma unroll
    for (int i = 0; i < FM; ++i)
        #pragma unroll
        for (int j = 0; j < FF; ++j)
            acc[i][j] = (f32x4)0.0f;

    auto stageA = [&](int buf, int ks) {
        #pragma unroll
        for (int j = 0; j < TBM / 64; ++j) {
            int c   = t + j * 256;
            int row = c >> 2;
            int cb  = (c & 3) * 8;        // halves
            int col = ks * BK + cb;
            int rg  = m0 + row;
            const _Float16* src;
            if constexpr (AMODE == 0 || AMODE == 3) {
                int rc = (rg < M) ? rg : 0;
                src = Aw + (u64)rc * Np + col;
            } else if constexpr (AMODE == 1) {
                int rc = (rg < M) ? rg : 0;
                int k = col >> FiLog, fi = col & (Fi - 1);
                src = Aw + (u64)idx[rc * 9 + k] * a_rs + b * Fi + fi;
            } else if constexpr (AMODE == 4) {
                int k = col >> FiLog, fi = col & (Fi - 1);
                src = Aw + (u64)k * a_rs + rg * Fi + fi;
            } else {  // 5
                int vo = rg >> 6, bb = rg & 63;
                int k = col >> FiLog, fi = col & (Fi - 1);
                src = Aw + (u64)idx[vo * 9 + k] * a_rs + bb * Fi + fi;
            }
            gl16(src, &sA[buf][row][cb]);
        }
    };
    auto stageB = [&](int buf, int ks) {
        constexpr int BCH = TBF * 4;  // 16B chunks
        if constexpr (BCH >= 256) {
            #pragma unroll
            for (int j = 0; j < BCH / 256; ++j) {
                int c = t + j * 256;
                int row = c >> 2, cb = (c & 3) * 8;
                gl16(Bw + (u64)(f0 + row) * Np + ks * BK + cb, &sB[buf][row][cb]);
            }
        } else {
            if (t < BCH) {
                int c = t;
                int row = c >> 2, cb = (c & 3) * 8;
                gl16(Bw + (u64)(f0 + row) * Np + ks * BK + cb, &sB[buf][row][cb]);
            }
        }
    };
    auto compute = [&](int buf) {
        half8 af[FM], bf[FF];
        #pragma unroll
        for (int i = 0; i < FM; ++i)
            af[i] = *(const half8*)&sA[buf][wm * (FM * 16) + i * 16 + lm][lg * 8];
        #pragma unroll
        for (int j = 0; j < FF; ++j)
            bf[j] = *(const half8*)&sB[buf][wf * (FF * 16) + j * 16 + lm][lg * 8];
        #pragma unroll
        for (int i = 0; i < FM; ++i)
            #pragma unroll
            for (int j = 0; j < FF; ++j)
                acc[i][j] = __builtin_amdgcn_mfma_f32_16x16x32_f16(af[i], bf[j], acc[i][j], 0, 0, 0);
    };

    if constexpr (AMODE == 2) {
        // single K-step: B via gload_lds, A via scalar gather stores
        stageB(0, 0);
        {
            int row = t >> 1;
            int base = (t & 1) * 16;
            int rg = m0 + row;
            #pragma unroll
            for (int q = 0; q < 16; ++q) {
                int n = base + q;
                _Float16 val = (_Float16)0.f;
                if (rg < M && n < 27) {
                    int k = n / 3, fi = n - k * 3;
                    val = Aw[(u64)idx[rg * 9 + k] * a_rs + b * 3 + fi];
                }
                sA[0][row][n] = val;
            }
        }
        __syncthreads();
        compute(0);
    } else {
        int kb = 0, ke = Np / BK;
        if constexpr (AMODE == 4) { kb = b * ksp; ke = kb + ksp; }
        stageA(0, kb);
        stageB(0, kb);
        int cur = 0;
        for (int ks = kb; ks < ke; ++ks) {
            __syncthreads();                       // drains vmcnt: buf[cur] ready
            if (ks + 1 < ke) { stageA(cur ^ 1, ks + 1); stageB(cur ^ 1, ks + 1); }
            compute(cur);
            cur ^= 1;
        }
    }

    // epilogue
    #pragma unroll
    for (int j = 0; j < FF; ++j) {
        int fl = f0 + wf * (FF * 16) + j * 16 + lm;
        float bv = 0.f;
        if (bias != nullptr && fl < F) bv = bias[fl];
        #pragma unroll
        for (int i = 0; i < FM; ++i) {
            #pragma unroll
            for (int r = 0; r < 4; ++r) {
                int m = m0 + wm * (FM * 16) + i * 16 + lg * 4 + r;
                float v = acc[i][j][r] + bv;
                if (flags & 1) v = (v > 0.f) ? v : expm1f(v);
                if constexpr (EPI == EPI_NAT) {
                    if (m < M && fl < F)
                        ((_Float16*)Cp)[(u64)m * c_rs + fl] = (_Float16)v;
                } else if constexpr (EPI == EPI_TR) {
                    if (m < Mp_out && fl < F) {
                        float o = (m < M && !((flags & 2) && m == M - 1)) ? v : 0.f;
                        ((_Float16*)Cp)[(u64)b * c_rs + (u64)fl * Mp_out + m] = (_Float16)o;
                    }
                } else if constexpr (EPI == EPI_FCD) {
                    if (m < M && fl < F)
                        ((_Float16*)Cp)[((u64)m * 256 + (fl & 255)) * 32 + (fl >> 8)] = (_Float16)v;
                } else if constexpr (EPI == EPI_PART) {
                    if (m < M && fl < F)
                        ((float*)Cp)[(u64)b * c_rs + (u64)m * F + fl] = v;
                } else {  // EPI_OUT (rows folded: m = v*64+b)
                    if (m < M && fl < F) {
                        int vo = m >> 6, bb = m & 63;
                        float o = ((flags & 2) && vo == Mp_out - 1) ? 0.f : v;
                        ((float*)Cp)[((u64)bb * Mp_out + vo) * 3 + fl] = o;
                    }
                }
            }
        }
    }
}

// ---- conversion / reduce kernels ----
__global__ void cvt_pool(const float* __restrict__ src, _Float16* __restrict__ dst,
                         int N, int Np)
{
    int n = blockIdx.x * 256 + threadIdx.x;
    if (n >= Np) return;
    u64 m = blockIdx.y;
    dst[m * Np + n] = (n < N) ? (_Float16)src[m * N + n] : (_Float16)0.f;
}

__global__ void cvt_T(const float* __restrict__ src, _Float16* __restrict__ dst,
                      int N, int F, int Np)
{
    int n = blockIdx.x * 256 + threadIdx.x;
    if (n >= Np) return;
    int f = blockIdx.y;
    dst[(u64)f * Np + n] = (n < N && f < F) ? (_Float16)src[(u64)n * F + f] : (_Float16)0.f;
}

__global__ void cvt_x(const float* __restrict__ src, _Float16* __restrict__ dst)
{
    int i = blockIdx.x * 256 + threadIdx.x;
    if (i >= 64 * 5024 * 3) return;
    int v = i / 192;
    int r = i - v * 192;
    int b = r / 3, c = r - b * 3;
    dst[i] = (_Float16)src[((u64)b * 5024 + v) * 3 + c];
}

__global__ void reduce_fce(const float* __restrict__ part, const float* __restrict__ bias,
                           _Float16* __restrict__ z)
{
    int i = blockIdx.x * 256 + threadIdx.x;  // 64*256
    int fl = i & 255;
    float s = bias[fl];
    #pragma unroll
    for (int p = 0; p < 8; ++p) s += part[(u64)p * 16384 + i];
    z[i] = (_Float16)s;
}

extern "C" void kernel_launch(void* const* d_in, const int* in_sizes, int n_in,
                              void* d_out, int out_size, void* d_ws, size_t ws_size,
                              hipStream_t stream)
{
    const float* x  = (const float*)d_in[0];
    const int* s0 = (const int*)d_in[1];
    const int* s1 = (const int*)d_in[2];
    const int* s2 = (const int*)d_in[3];
    const int* s3 = (const int*)d_in[4];
    const float* D0 = (const float*)d_in[5];
    const float* U0_ = (const float*)d_in[6];
    const float* D1 = (const float*)d_in[7];
    const float* U1_ = (const float*)d_in[8];
    const float* D2 = (const float*)d_in[9];
    const float* U2_ = (const float*)d_in[10];
    const float* D3 = (const float*)d_in[11];
    const float* U3_ = (const float*)d_in[12];
    const float* We0 = (const float*)d_in[13]; const float* be0 = (const float*)d_in[14];
    const float* We1 = (const float*)d_in[15]; const float* be1 = (const float*)d_in[16];
    const float* We2 = (const float*)d_in[17]; const float* be2 = (const float*)d_in[18];
    const float* We3 = (const float*)d_in[19]; const float* be3 = (const float*)d_in[20];
    const float* fceW = (const float*)d_in[21]; const float* fceb = (const float*)d_in[22];
    const float* fcdW = (const float*)d_in[23]; const float* fcdb = (const float*)d_in[24];
    const float* Wd0 = (const float*)d_in[25]; const float* bd0 = (const float*)d_in[26];
    const float* Wd1 = (const float*)d_in[27]; const float* bd1 = (const float*)d_in[28];
    const float* Wd2 = (const float*)d_in[29]; const float* bd2 = (const float*)d_in[30];
    const float* Wd3 = (const float*)d_in[31]; const float* bd3 = (const float*)d_in[32];

    _Float16* W = (_Float16*)d_ws;
    size_t off = 0;
    auto alloc = [&](size_t e) { size_t o = off; off += (e + 255) & ~(size_t)255; return o; };

    const size_t oActV = alloc((size_t)5024 * 4096);   // [vertex][(b,f)]
    const size_t oActT = alloc((size_t)4096 * 5024);   // [b][f][vertex_padded]
    const size_t oZ    = alloc((size_t)64 * 256);
    const size_t oPart = alloc((size_t)8 * 64 * 256 * 2);  // fp32 partials (half-elems)
    const size_t oU3in = alloc((size_t)16384 * 32);
    const size_t oXp   = alloc((size_t)5024 * 192);
    const size_t oD0 = alloc((size_t)1257 * 5024);
    const size_t oU0 = alloc((size_t)5024 * 1280);
    const size_t oD1 = alloc((size_t)315 * 1280);
    const size_t oU1 = alloc((size_t)1257 * 320);
    const size_t oD2 = alloc((size_t)80 * 320);
    const size_t oU2 = alloc((size_t)315 * 96);
    const size_t oD3 = alloc((size_t)21 * 96);
    const size_t oU3 = alloc((size_t)80 * 32);
    const size_t oWe0 = alloc((size_t)64 * 32);
    const size_t oWe1 = alloc((size_t)64 * 576);
    const size_t oWe2 = alloc((size_t)128 * 576);
    const size_t oWe3 = alloc((size_t)256 * 1152);
    const size_t oFce = alloc((size_t)256 * 5376);
    const size_t oFcW = alloc((size_t)5376 * 256);
    const size_t oWd0 = alloc((size_t)128 * 2304);
    const size_t oWd1 = alloc((size_t)64 * 1152);
    const size_t oWd2 = alloc((size_t)64 * 576);
    const size_t oWd3 = alloc((size_t)16 * 576);

    // ---- conversions ----
    cvt_x<<<dim3((64 * 5024 * 3 + 255) / 256), 256, 0, stream>>>(x, W + oXp);
    auto cpool = [&](const float* src, size_t o, int M_, int N_, int Np_) {
        cvt_pool<<<dim3((Np_ + 255) / 256, M_), 256, 0, stream>>>(src, W + o, N_, Np_);
    };
    auto cT = [&](const float* src, size_t o, int N_, int F_, int Np_, int Fp_) {
        cvt_T<<<dim3((Np_ + 255) / 256, Fp_), 256, 0, stream>>>(src, W + o, N_, F_, Np_);
    };
    cpool(D0, oD0, 1257, 5024, 5024);
    cpool(U0_, oU0, 5024, 1257, 1280);
    cpool(D1, oD1, 315, 1257, 1280);
    cpool(U1_, oU1, 1257, 315, 320);
    cpool(D2, oD2, 80, 315, 320);
    cpool(U2_, oU2, 315, 80, 96);
    cpool(D3, oD3, 21, 80, 96);
    cpool(U3_, oU3, 80, 21, 32);
    cT(We0, oWe0, 27, 64, 32, 64);
    cT(We1, oWe1, 576, 64, 576, 64);
    cT(We2, oWe2, 576, 128, 576, 128);
    cT(We3, oWe3, 1152, 256, 1152, 256);
    cT(fceW, oFce, 5376, 256, 5376, 256);
    cT(fcdW, oFcW, 256, 5376, 256, 5376);
    cT(Wd0, oWd0, 2304, 128, 2304, 128);
    cT(Wd1, oWd1, 1152, 64, 1152, 64);
    cT(Wd2, oWd2, 576, 64, 576, 64);
    cT(Wd3, oWd3, 576, 3, 576, 16);

    #define GEMM(AM, EP, BM_, BF_, WM_, WF_, gx, gy, gz, Aw_, ars_, idx_, FiL_, Bw_, bias_, Cp_, crs_, Mp_, M_, Np_, F_, fl_, ksp_) \
        gemm_k<AM, EP, BM_, BF_, WM_, WF_><<<dim3(gx, gy, gz), 256, 0, stream>>>( \
            Aw_, ars_, idx_, FiL_, Bw_, bias_, Cp_, crs_, Mp_, M_, Np_, F_, fl_, ksp_)

    // ---- encoder ----
    GEMM(2, EPI_TR, 128, 64, 2, 2, 1, 40, 64, W + oXp, 192, s0, 0,
         W + oWe0, be0, W + oActT, (u64)64 * 5024, 5024, 5024, 32, 64, 3, 0);
    GEMM(0, EPI_NAT, 64, 128, 2, 2, 32, 20, 1, W + oD0, 0, nullptr, 0,
         W + oActT, nullptr, W + oActV, 4096, 0, 1257, 5024, 4096, 0, 0);
    GEMM(1, EPI_TR, 128, 64, 2, 2, 1, 10, 64, W + oActV, 4096, s1, 6,
         W + oWe1, be1, W + oActT, (u64)64 * 1280, 1280, 1257, 576, 64, 3, 0);
    GEMM(0, EPI_NAT, 64, 128, 2, 2, 32, 5, 1, W + oD1, 0, nullptr, 0,
         W + oActT, nullptr, W + oActV, 4096, 0, 315, 1280, 4096, 0, 0);
    GEMM(1, EPI_TR, 128, 64, 2, 2, 2, 3, 64, W + oActV, 4096, s2, 6,
         W + oWe2, be2, W + oActT, (u64)128 * 320, 320, 315, 576, 128, 3, 0);
    GEMM(0, EPI_NAT, 64, 128, 2, 2, 64, 2, 1, W + oD2, 0, nullptr, 0,
         W + oActT, nullptr, W + oActV, 8192, 0, 80, 320, 8192, 0, 0);
    GEMM(1, EPI_TR, 128, 64, 2, 2, 4, 1, 64, W + oActV, 8192, s3, 7,
         W + oWe3, be3, W + oActT, (u64)256 * 96, 96, 80, 1152, 256, 3, 0);
    GEMM(0, EPI_NAT, 64, 128, 2, 2, 128, 1, 1, W + oD3, 0, nullptr, 0,
         W + oActT, nullptr, W + oActV, 16384, 0, 21, 96, 16384, 0, 0);
    // ---- bottleneck ----
    GEMM(4, EPI_PART, 64, 64, 2, 2, 4, 1, 8, W + oActV, 16384, nullptr, 8,
         W + oFce, nullptr, W + oPart, (u64)64 * 256, 0, 64, 5376, 256, 0, 21);
    reduce_fce<<<dim3(64), 256, 0, stream>>>((const float*)(W + oPart), fceb, W + oZ);
    hipMemsetAsync(W + oU3in, 0, (size_t)16384 * 32 * sizeof(_Float16), stream);
    GEMM(3, EPI_FCD, 64, 128, 2, 2, 42, 1, 1, W + oZ, 0, nullptr, 0,
         W + oFcW, fcdb, W + oU3in, 0, 0, 64, 256, 5376, 0, 0);
    // ---- decoder ----
    GEMM(0, EPI_NAT, 64, 128, 2, 2, 128, 2, 1, W + oU3, 0, nullptr, 0,
         W + oU3in, nullptr, W + oActV, 16384, 0, 80, 32, 16384, 0, 0);
    GEMM(1, EPI_TR, 128, 64, 2, 2, 2, 1, 64, W + oActV, 16384, s3, 8,
         W + oWd0, bd0, W + oActT, (u64)128 * 96, 96, 80, 2304, 128, 3, 0);
    GEMM(0, EPI_NAT, 64, 128, 2, 2, 64, 5, 1, W + oU2, 0, nullptr, 0,
         W + oActT, nullptr, W + oActV, 8192, 0, 315, 96, 8192, 0, 0);
    GEMM(1, EPI_TR, 128, 64, 2, 2, 1, 3, 64, W + oActV, 8192, s2, 7,
         W + oWd1, bd1, W + oActT, (u64)64 * 320, 320, 315, 1152, 64, 3, 0);
    GEMM(0, EPI_NAT, 64, 128, 2, 2, 32, 20, 1, W + oU1, 0, nullptr, 0,
         W + oActT, nullptr, W + oActV, 4096, 0, 1257, 320, 4096, 0, 0);
    GEMM(1, EPI_TR, 128, 64, 2, 2, 1, 10, 64, W + oActV, 4096, s1, 6,
         W + oWd2, bd2, W + oActT, (u64)64 * 1280, 1280, 1257, 576, 64, 3, 0);
    GEMM(0, EPI_NAT, 128, 128, 2, 2, 32, 40, 1, W + oU0, 0, nullptr, 0,
         W + oActT, nullptr, W + oActV, 4096, 0, 5024, 1280, 4096, 0, 0);
    GEMM(5, EPI_OUT, 128, 16, 4, 1, 1, 2512, 1, W + oActV, 4096, s0, 6,
         W + oWd3, bd3, d_out, 0, 5024, 321536, 576, 3, 2, 0);
    #undef GEMM
}

// Round 6
// 631.823 us; speedup vs baseline: 7.6877x; 1.1204x over previous
//
#include <hip/hip_runtime.h>
#include <math.h>

typedef __attribute__((ext_vector_type(8))) _Float16 half8;
typedef __attribute__((ext_vector_type(4))) float f32x4;
typedef unsigned long long u64;

#define BK 32

#define EPI_NAT  0
#define EPI_TR   1
#define EPI_FCD  2
#define EPI_OUT  3
#define EPI_PART 4

typedef const __attribute__((address_space(1))) void* gas1;
typedef __attribute__((address_space(3))) void* las3;

__device__ __forceinline__ void gl16(const void* g, void* l) {
    __builtin_amdgcn_global_load_lds((gas1)g, (las3)l, 16, 0, 0);
}
template<int N> __device__ __forceinline__ void vwait() {
    asm volatile("s_waitcnt vmcnt(%0)" :: "n"(N) : "memory");
}
__device__ __forceinline__ void barx() {
    asm volatile("" ::: "memory");
    __builtin_amdgcn_s_barrier();
    asm volatile("" ::: "memory");
}

// AMODE: 0 pool  (A [M][Np] fp16; B = actT rows=(b,f))
//        1 sconv (A gathered from actV via idx(LDS), z=batch; B weightsT)
//        2 sconv0 (A scalar gather Fi=3, nk=1; B weightsT)
//        3 fc    (A plain [M][Np]; B weightsT)
//        4 fc-enc split-K (A from actV, rows=batch; z=K-slice; B weightsT)
//        5 sconv rows-folded (rows = v*64+b; B weightsT)  [Wd3]
template<int AMODE, int EPI, int TBM, int TBF, int WM, int WF>
__global__ __launch_bounds__(256) void gemm_k(
    const _Float16* __restrict__ Aw, u64 a_rs,
    const int* __restrict__ idx, int FiLog,
    const _Float16* __restrict__ Bw,
    const float* __restrict__ bias,
    void* __restrict__ Cp, u64 c_rs, int Mp_out,
    int M, int Np, int F, int flags, int ksp)   // flags: bit0 ELU, bit1 zeroLast
{
    constexpr int FM = TBM / WM / 16;
    constexpr int FF = TBF / WF / 16;
    constexpr int LPS_A = TBM / 64;
    constexpr bool BSM = (TBF < 64);
    constexpr int LPS_B = BSM ? 0 : TBF / 64;
    constexpr int LW0 = LPS_A + (BSM ? 1 : LPS_B);   // loads/stage, wave 0
    constexpr int LWX = LPS_A + LPS_B;               // loads/stage, other waves
    constexpr int NI = (AMODE == 1) ? TBM : 2;

    __shared__ _Float16 sA[3][TBM][BK];
    __shared__ _Float16 sB[3][TBF][BK];
    __shared__ int sIdx[NI][9];

    const int t  = threadIdx.x;
    const int b  = blockIdx.z;
    const int m0 = blockIdx.y * TBM;
    const int f0 = blockIdx.x * TBF;
    const int lane = t & 63;
    const int wid  = t >> 6;
    const int wm = wid / WF;
    const int wf = wid % WF;
    const int lm = lane & 15;
    const int lg = lane >> 4;
    const int Fi = 1 << FiLog;

    f32x4 acc[FM][FF];
    #pragma unroll
    for (int i = 0; i < FM; ++i)
        #pragma unroll
        for (int j = 0; j < FF; ++j)
            acc[i][j] = (f32x4)0.0f;

    // ---- spiral-index prefetch to LDS (keeps vmcnt stream pure gl16) ----
    if constexpr (AMODE == 1) {
        for (int i = t; i < TBM * 9; i += 256) {
            int r = i / 9, k = i - r * 9;
            int rc = m0 + r; if (rc >= M) rc = M - 1;
            sIdx[r][k] = idx[rc * 9 + k];
        }
        __syncthreads();
    } else if constexpr (AMODE == 5) {
        if (t < 18) {
            int r = t / 9, k = t - r * 9;
            sIdx[r][k] = idx[((m0 >> 6) + r) * 9 + k];
        }
        __syncthreads();
    }

    auto stage = [&](int buf, int ks) {
        if constexpr (AMODE != 2) {
            #pragma unroll
            for (int j = 0; j < LPS_A; ++j) {
                int c   = t + j * 256;
                int row = c >> 2;
                int sw  = ((c & 3) ^ (row & 3)) * 8;   // swizzled source chunk
                int col = ks * BK + sw;
                const _Float16* src;
                if constexpr (AMODE == 0 || AMODE == 3) {
                    int rc = m0 + row; if (rc >= M) rc = M - 1;
                    src = Aw + (u64)rc * Np + col;
                } else if constexpr (AMODE == 1) {
                    int k = col >> FiLog, fi = col & (Fi - 1);
                    src = Aw + (u64)sIdx[row][k] * a_rs + b * Fi + fi;
                } else if constexpr (AMODE == 4) {
                    int k = col >> FiLog, fi = col & (Fi - 1);
                    src = Aw + (u64)k * a_rs + (m0 + row) * Fi + fi;
                } else {  // 5
                    int k = col >> FiLog, fi = col & (Fi - 1);
                    int bb = (m0 + row) & 63;
                    src = Aw + (u64)sIdx[row >> 6][k] * a_rs + bb * Fi + fi;
                }
                gl16(src, &sA[buf][row][(c & 3) * 8]);   // linear dest (lane*16)
            }
        }
        if constexpr (!BSM) {
            #pragma unroll
            for (int j = 0; j < LPS_B; ++j) {
                int c   = t + j * 256;
                int row = c >> 2;
                int sw  = ((c & 3) ^ (row & 3)) * 8;
                gl16(Bw + (u64)(f0 + row) * Np + ks * BK + sw, &sB[buf][row][(c & 3) * 8]);
            }
        } else {
            if (wid == 0) {
                int c   = t;                 // 0..63
                int row = c >> 2;
                int sw  = ((c & 3) ^ (row & 3)) * 8;
                gl16(Bw + (u64)(f0 + row) * Np + ks * BK + sw, &sB[buf][row][(c & 3) * 8]);
            }
        }
    };

    auto compute = [&](int buf) {
        const int sa = (lg ^ (lm & 3)) * 8;   // un-swizzle on read
        half8 af[FM], bf[FF];
        #pragma unroll
        for (int i = 0; i < FM; ++i)
            af[i] = *(const half8*)&sA[buf][wm * (FM * 16) + i * 16 + lm][sa];
        #pragma unroll
        for (int j = 0; j < FF; ++j)
            bf[j] = *(const half8*)&sB[buf][wf * (FF * 16) + j * 16 + lm][sa];
        #pragma unroll
        for (int i = 0; i < FM; ++i)
            #pragma unroll
            for (int j = 0; j < FF; ++j)
                acc[i][j] = __builtin_amdgcn_mfma_f32_16x16x32_f16(af[i], bf[j], acc[i][j], 0, 0, 0);
    };

    if constexpr (AMODE == 2) {
        stage(0, 0);   // B only
        {
            int row = t >> 1;
            int base = (t & 1) * 16;
            int rg = m0 + row;
            #pragma unroll
            for (int q = 0; q < 16; ++q) {
                int n = base + q;
                _Float16 val = (_Float16)0.f;
                if (rg < M && n < 27) {
                    int k = n / 3, fi = n - k * 3;
                    val = Aw[(u64)idx[rg * 9 + k] * a_rs + b * 3 + fi];
                }
                int ch = n >> 3;
                sA[0][row][((ch ^ (row & 3)) * 8) + (n & 7)] = val;   // store swizzled
            }
        }
        __syncthreads();
        compute(0);
    } else {
        int kb = 0, ke = Np / BK;
        if constexpr (AMODE == 4) { kb = b * ksp; ke = kb + ksp; }
        stage(0, kb);
        if (kb + 1 < ke) stage(1, kb + 1);
        if (kb + 2 < ke) stage(2, kb + 2);
        int cur = 0;
        for (int ks = kb; ks < ke; ++ks) {
            int rem = ke - ks;
            if (rem >= 3) {
                if constexpr (LW0 == LWX) vwait<2 * LW0>();
                else { if (wid == 0) vwait<2 * LW0>(); else vwait<2 * LWX>(); }
            } else if (rem == 2) {
                if constexpr (LW0 == LWX) vwait<LW0>();
                else { if (wid == 0) vwait<LW0>(); else vwait<LWX>(); }
            } else {
                vwait<0>();
            }
            barx();                       // buf[cur] landed, all waves synced
            compute(cur);
            barx();                       // all waves done reading buf[cur]
            if (ks + 3 < ke) stage(cur, ks + 3);
            cur = (cur == 2) ? 0 : cur + 1;
        }
    }

    // ---- epilogue ----
    #pragma unroll
    for (int j = 0; j < FF; ++j) {
        int fl = f0 + wf * (FF * 16) + j * 16 + lm;
        float bv = 0.f;
        if (bias != nullptr && fl < F) bv = bias[fl];
        #pragma unroll
        for (int i = 0; i < FM; ++i) {
            #pragma unroll
            for (int r = 0; r < 4; ++r) {
                int m = m0 + wm * (FM * 16) + i * 16 + lg * 4 + r;
                float v = acc[i][j][r] + bv;
                if (flags & 1) v = (v > 0.f) ? v : expm1f(v);
                if constexpr (EPI == EPI_NAT) {
                    if (m < M && fl < F)
                        ((_Float16*)Cp)[(u64)m * c_rs + fl] = (_Float16)v;
                } else if constexpr (EPI == EPI_TR) {
                    if (m < Mp_out && fl < F) {
                        float o = (m < M && !((flags & 2) && m == M - 1)) ? v : 0.f;
                        ((_Float16*)Cp)[(u64)b * c_rs + (u64)fl * Mp_out + m] = (_Float16)o;
                    }
                } else if constexpr (EPI == EPI_FCD) {
                    if (m < M && fl < F)
                        ((_Float16*)Cp)[((u64)m * 256 + (fl & 255)) * 32 + (fl >> 8)] = (_Float16)v;
                } else if constexpr (EPI == EPI_PART) {
                    if (m < M && fl < F)
                        ((float*)Cp)[(u64)b * c_rs + (u64)m * F + fl] = v;
                } else {  // EPI_OUT (rows folded: m = v*64+b)
                    if (m < M && fl < F) {
                        int vo = m >> 6, bb = m & 63;
                        float o = ((flags & 2) && vo == Mp_out - 1) ? 0.f : v;
                        ((float*)Cp)[((u64)bb * Mp_out + vo) * 3 + fl] = o;
                    }
                }
            }
        }
    }
}

// ---- fused weight conversion ----
struct CvtPtrs { const float* p[18]; };

constexpr int CV_R[18]  = {1257,5024,315,1257,80,315,21,80,  64,64,128,256,256,5376,128,64,64,16};
constexpr int CV_N[18]  = {5024,1257,1257,315,315,80,80,21,  27,576,576,1152,5376,256,2304,1152,576,576};
constexpr int CV_NP[18] = {5024,1280,1280,320,320,96,96,32,  32,576,576,1152,5376,256,2304,1152,576,576};
constexpr int CV_F[18]  = {0,0,0,0,0,0,0,0,  64,64,128,256,256,5376,128,64,64,3};

constexpr u64 cv_elems(int i) { return (u64)CV_R[i] * CV_NP[i]; }
constexpr u64 cv_off(int i) { u64 o = 0; for (int j = 0; j < i; ++j) o += (cv_elems(j) + 255) & ~(u64)255; return o; }
constexpr int cv_blk(int i) { return (int)((cv_elems(i) + 255) >> 8); }
constexpr int cv_start(int i) { int s = 0; for (int j = 0; j < i; ++j) s += cv_blk(j); return s; }

__global__ __launch_bounds__(256) void cvt_all(CvtPtrs ps, _Float16* __restrict__ dst)
{
    const int bx = blockIdx.x, t = threadIdx.x;
    #pragma unroll
    for (int i = 0; i < 18; ++i) {
        if (bx >= cv_start(i) && bx < cv_start(i + 1)) {
            const u64 e = (u64)(bx - cv_start(i)) * 256 + t;
            if (e < cv_elems(i)) {
                const int NP = CV_NP[i], N = CV_N[i], Fo = CV_F[i];
                int row = (int)(e / (u64)NP);
                int col = (int)(e - (u64)row * NP);
                float v = 0.f;
                const float* s = ps.p[i];
                if (Fo == 0) { if (col < N) v = s[(u64)row * N + col]; }
                else         { if (col < N && row < Fo) v = s[(u64)col * Fo + row]; }
                dst[cv_off(i) + e] = (_Float16)v;
            }
        }
    }
}

__global__ void cvt_x(const float* __restrict__ src, _Float16* __restrict__ dst)
{
    int i = blockIdx.x * 256 + threadIdx.x;
    if (i >= 64 * 5024 * 3) return;
    int v = i / 192;
    int r = i - v * 192;
    int b = r / 3, c = r - b * 3;
    dst[i] = (_Float16)src[((u64)b * 5024 + v) * 3 + c];
}

__global__ void reduce_fce(const float* __restrict__ part, const float* __restrict__ bias,
                           _Float16* __restrict__ z)
{
    int i = blockIdx.x * 256 + threadIdx.x;  // 64*256
    int fl = i & 255;
    float s = bias[fl];
    #pragma unroll
    for (int p = 0; p < 8; ++p) s += part[(u64)p * 16384 + i];
    z[i] = (_Float16)s;
}

extern "C" void kernel_launch(void* const* d_in, const int* in_sizes, int n_in,
                              void* d_out, int out_size, void* d_ws, size_t ws_size,
                              hipStream_t stream)
{
    const float* x  = (const float*)d_in[0];
    const int* s0 = (const int*)d_in[1];
    const int* s1 = (const int*)d_in[2];
    const int* s2 = (const int*)d_in[3];
    const int* s3 = (const int*)d_in[4];
    const float* be0 = (const float*)d_in[14];
    const float* be1 = (const float*)d_in[16];
    const float* be2 = (const float*)d_in[18];
    const float* be3 = (const float*)d_in[20];
    const float* fceb = (const float*)d_in[22];
    const float* fcdb = (const float*)d_in[24];
    const float* bd0 = (const float*)d_in[26];
    const float* bd1 = (const float*)d_in[28];
    const float* bd2 = (const float*)d_in[30];
    const float* bd3 = (const float*)d_in[32];

    _Float16* W = (_Float16*)d_ws;
    size_t off = 0;
    auto alloc = [&](size_t e) { size_t o = off; off += (e + 255) & ~(size_t)255; return o; };

    const size_t oActV = alloc((size_t)5024 * 4096);   // [vertex][(b,f)]
    const size_t oActT = alloc((size_t)4096 * 5024);   // [b][f][vertex_padded]
    const size_t oZ    = alloc((size_t)64 * 256);
    const size_t oPart = alloc((size_t)8 * 64 * 256 * 2);  // fp32 partials
    const size_t oU3in = alloc((size_t)16384 * 32);
    const size_t oXp   = alloc((size_t)5024 * 192);
    const size_t oCvt  = alloc((size_t)(cv_off(17) + ((cv_elems(17) + 255) & ~(u64)255)));
    auto wofs = [&](int i) { return oCvt + (size_t)cv_off(i); };

    // ---- conversions (2 launches) ----
    cvt_x<<<dim3((64 * 5024 * 3 + 255) / 256), 256, 0, stream>>>(x, W + oXp);
    {
        CvtPtrs ps;
        ps.p[0] = (const float*)d_in[5];   // D0
        ps.p[1] = (const float*)d_in[6];   // U0
        ps.p[2] = (const float*)d_in[7];   // D1
        ps.p[3] = (const float*)d_in[8];   // U1
        ps.p[4] = (const float*)d_in[9];   // D2
        ps.p[5] = (const float*)d_in[10];  // U2
        ps.p[6] = (const float*)d_in[11];  // D3
        ps.p[7] = (const float*)d_in[12];  // U3
        ps.p[8] = (const float*)d_in[13];  // We0
        ps.p[9] = (const float*)d_in[15];  // We1
        ps.p[10] = (const float*)d_in[17]; // We2
        ps.p[11] = (const float*)d_in[19]; // We3
        ps.p[12] = (const float*)d_in[21]; // fceW
        ps.p[13] = (const float*)d_in[23]; // fcdW
        ps.p[14] = (const float*)d_in[25]; // Wd0
        ps.p[15] = (const float*)d_in[27]; // Wd1
        ps.p[16] = (const float*)d_in[29]; // Wd2
        ps.p[17] = (const float*)d_in[31]; // Wd3
        cvt_all<<<dim3(cv_start(18)), 256, 0, stream>>>(ps, W + oCvt);
    }
    hipMemsetAsync(W + oU3in, 0, (size_t)16384 * 32 * sizeof(_Float16), stream);

    #define GEMM(AM, EP, BM_, BF_, WM_, WF_, gx, gy, gz, Aw_, ars_, idx_, FiL_, Bw_, bias_, Cp_, crs_, Mp_, M_, Np_, F_, fl_, ksp_) \
        gemm_k<AM, EP, BM_, BF_, WM_, WF_><<<dim3(gx, gy, gz), 256, 0, stream>>>( \
            Aw_, ars_, idx_, FiL_, Bw_, bias_, Cp_, crs_, Mp_, M_, Np_, F_, fl_, ksp_)

    // ---- encoder ----
    GEMM(2, EPI_TR, 128, 64, 2, 2, 1, 40, 64, W + oXp, 192, s0, 0,
         W + wofs(8), be0, W + oActT, (u64)64 * 5024, 5024, 5024, 32, 64, 3, 0);
    GEMM(0, EPI_NAT, 64, 128, 2, 2, 32, 20, 1, W + wofs(0), 0, nullptr, 0,
         W + oActT, nullptr, W + oActV, 4096, 0, 1257, 5024, 4096, 0, 0);
    GEMM(1, EPI_TR, 128, 64, 2, 2, 1, 10, 64, W + oActV, 4096, s1, 6,
         W + wofs(9), be1, W + oActT, (u64)64 * 1280, 1280, 1257, 576, 64, 3, 0);
    GEMM(0, EPI_NAT, 64, 128, 2, 2, 32, 5, 1, W + wofs(2), 0, nullptr, 0,
         W + oActT, nullptr, W + oActV, 4096, 0, 315, 1280, 4096, 0, 0);
    GEMM(1, EPI_TR, 128, 64, 2, 2, 2, 3, 64, W + oActV, 4096, s2, 6,
         W + wofs(10), be2, W + oActT, (u64)128 * 320, 320, 315, 576, 128, 3, 0);
    GEMM(0, EPI_NAT, 64, 128, 2, 2, 64, 2, 1, W + wofs(4), 0, nullptr, 0,
         W + oActT, nullptr, W + oActV, 8192, 0, 80, 320, 8192, 0, 0);
    GEMM(1, EPI_TR, 128, 64, 2, 2, 4, 1, 64, W + oActV, 8192, s3, 7,
         W + wofs(11), be3, W + oActT, (u64)256 * 96, 96, 80, 1152, 256, 3, 0);
    GEMM(0, EPI_NAT, 64, 128, 2, 2, 128, 1, 1, W + wofs(6), 0, nullptr, 0,
         W + oActT, nullptr, W + oActV, 16384, 0, 21, 96, 16384, 0, 0);
    // ---- bottleneck ----
    GEMM(4, EPI_PART, 64, 64, 2, 2, 4, 1, 8, W + oActV, 16384, nullptr, 8,
         W + wofs(12), nullptr, W + oPart, (u64)64 * 256, 0, 64, 5376, 256, 0, 21);
    reduce_fce<<<dim3(64), 256, 0, stream>>>((const float*)(W + oPart), fceb, W + oZ);
    GEMM(3, EPI_FCD, 64, 128, 2, 2, 42, 1, 1, W + oZ, 0, nullptr, 0,
         W + wofs(13), fcdb, W + oU3in, 0, 0, 64, 256, 5376, 0, 0);
    // ---- decoder ----
    GEMM(0, EPI_NAT, 64, 128, 2, 2, 128, 2, 1, W + wofs(7), 0, nullptr, 0,
         W + oU3in, nullptr, W + oActV, 16384, 0, 80, 32, 16384, 0, 0);
    GEMM(1, EPI_TR, 128, 64, 2, 2, 2, 1, 64, W + oActV, 16384, s3, 8,
         W + wofs(14), bd0, W + oActT, (u64)128 * 96, 96, 80, 2304, 128, 3, 0);
    GEMM(0, EPI_NAT, 64, 128, 2, 2, 64, 5, 1, W + wofs(5), 0, nullptr, 0,
         W + oActT, nullptr, W + oActV, 8192, 0, 315, 96, 8192, 0, 0);
    GEMM(1, EPI_TR, 128, 64, 2, 2, 1, 3, 64, W + oActV, 8192, s2, 7,
         W + wofs(15), bd1, W + oActT, (u64)64 * 320, 320, 315, 1152, 64, 3, 0);
    GEMM(0, EPI_NAT, 64, 128, 2, 2, 32, 20, 1, W + wofs(3), 0, nullptr, 0,
         W + oActT, nullptr, W + oActV, 4096, 0, 1257, 320, 4096, 0, 0);
    GEMM(1, EPI_TR, 128, 64, 2, 2, 1, 10, 64, W + oActV, 4096, s1, 6,
         W + wofs(16), bd2, W + oActT, (u64)64 * 1280, 1280, 1257, 576, 64, 3, 0);
    GEMM(0, EPI_NAT, 128, 128, 2, 2, 32, 40, 1, W + wofs(1), 0, nullptr, 0,
         W + oActT, nullptr, W + oActV, 4096, 0, 5024, 1280, 4096, 0, 0);
    GEMM(5, EPI_OUT, 128, 16, 4, 1, 1, 2512, 1, W + oActV, 4096, s0, 6,
         W + wofs(17), bd3, d_out, 0, 5024, 321536, 576, 3, 2, 0);
    #undef GEMM
}

// Round 7
// 620.602 us; speedup vs baseline: 7.8267x; 1.0181x over previous
//
#include <hip/hip_runtime.h>
#include <math.h>

typedef __attribute__((ext_vector_type(8))) _Float16 half8;
typedef __attribute__((ext_vector_type(4))) float f32x4;
typedef unsigned long long u64;

#define BK 32

#define EPI_NAT  0
#define EPI_TR   1
#define EPI_FCD  2
#define EPI_OUT  3
#define EPI_PART 4

typedef const __attribute__((address_space(1))) void* gas1;
typedef __attribute__((address_space(3))) void* las3;

__device__ __forceinline__ void gl16(const void* g, void* l) {
    __builtin_amdgcn_global_load_lds((gas1)g, (las3)l, 16, 0, 0);
}
template<int N> __device__ __forceinline__ void vwait() {
    asm volatile("s_waitcnt vmcnt(%0)" :: "n"(N) : "memory");
}
__device__ __forceinline__ void barx() {
    asm volatile("" ::: "memory");
    __builtin_amdgcn_s_barrier();
    asm volatile("" ::: "memory");
}

// ============ big-pool kernel: 512 threads, 8 waves, TBF=256, BK=64 ============
// A [M][Np] fp16 (rows clamped), B [4096][Np] fp16 (actT), C [M][4096] fp16 (actV)
template<int TBM>
__global__ __launch_bounds__(512, 2) void pool_k(
    const _Float16* __restrict__ Aw, const _Float16* __restrict__ Bw,
    _Float16* __restrict__ Cp, int M, int Np, u64 c_rs)
{
    constexpr int WSM = (TBM == 256) ? 128 : 64;   // per-wave m span (2 wave-rows)
    constexpr int FM  = WSM / 16;
    constexpr int ACH = TBM * 8 / 512;             // A 16B-chunks per thread
    constexpr int LPS = ACH + 4;                   // loads per stage per thread

    __shared__ _Float16 sA[2][TBM][64];
    __shared__ _Float16 sB[2][256][64];

    const int t  = threadIdx.x;
    const int m0 = blockIdx.y * TBM;
    const int f0 = blockIdx.x * 256;
    const int lane = t & 63;
    const int wid  = t >> 6;
    const int wm = wid >> 2;     // 0..1
    const int wf = wid & 3;      // 0..3
    const int lm = lane & 15;
    const int lg = lane >> 4;

    f32x4 acc[FM][4];
    #pragma unroll
    for (int i = 0; i < FM; ++i)
        #pragma unroll
        for (int j = 0; j < 4; ++j)
            acc[i][j] = (f32x4)0.0f;

    auto stage = [&](int buf, int ks) {
        #pragma unroll
        for (int j = 0; j < ACH; ++j) {
            int c   = t + j * 512;
            int row = c >> 3;
            int gch = (c & 7) ^ (row & 7);          // pre-swizzled source chunk
            int rc  = m0 + row; if (rc >= M) rc = M - 1;
            gl16(Aw + (u64)rc * Np + ks * 64 + gch * 8,
                 (_Float16*)&sA[buf][0][0] + (u64)c * 8);   // linear dest
        }
        #pragma unroll
        for (int j = 0; j < 4; ++j) {
            int c   = t + j * 512;
            int row = c >> 3;
            int gch = (c & 7) ^ (row & 7);
            gl16(Bw + (u64)(f0 + row) * Np + ks * 64 + gch * 8,
                 (_Float16*)&sB[buf][0][0] + (u64)c * 8);
        }
    };

    auto compute = [&](int buf) {
        #pragma unroll
        for (int kh = 0; kh < 2; ++kh) {
            half8 af[FM], bf[4];
            #pragma unroll
            for (int i = 0; i < FM; ++i) {
                int row = wm * WSM + i * 16 + lm;
                int ch  = (kh * 4 + lg) ^ (lm & 7);
                af[i] = *(const half8*)&sA[buf][row][ch * 8];
            }
            #pragma unroll
            for (int j = 0; j < 4; ++j) {
                int row = wf * 64 + j * 16 + lm;
                int ch  = (kh * 4 + lg) ^ (lm & 7);
                bf[j] = *(const half8*)&sB[buf][row][ch * 8];
            }
            #pragma unroll
            for (int i = 0; i < FM; ++i)
                #pragma unroll
                for (int j = 0; j < 4; ++j)
                    acc[i][j] = __builtin_amdgcn_mfma_f32_16x16x32_f16(af[i], bf[j], acc[i][j], 0, 0, 0);
        }
    };

    const int ke = Np / 64;
    stage(0, 0);
    int cur = 0;
    for (int ks = 0; ks < ke; ++ks) {
        if (ks + 1 < ke) { stage(cur ^ 1, ks + 1); vwait<LPS>(); }
        else             { vwait<0>(); }
        barx();
        compute(cur);
        barx();
        cur ^= 1;
    }

    #pragma unroll
    for (int j = 0; j < 4; ++j) {
        int fl = f0 + wf * 64 + j * 16 + lm;
        #pragma unroll
        for (int i = 0; i < FM; ++i) {
            #pragma unroll
            for (int r = 0; r < 4; ++r) {
                int m = m0 + wm * WSM + i * 16 + lg * 4 + r;
                if (m < M)
                    Cp[(u64)m * c_rs + fl] = (_Float16)acc[i][j][r];
            }
        }
    }
}

// ============ general kernel (sconv / small pools / fc) ============
// AMODE: 0 pool, 1 sconv gather (idx via LDS), 2 sconv0 (Fi=3, nk=1),
//        3 fc, 4 fc-enc split-K, 5 sconv rows-folded [Wd3]
template<int AMODE, int EPI, int TBM, int TBF, int WM, int WF>
__global__ __launch_bounds__(256) void gemm_k(
    const _Float16* __restrict__ Aw, u64 a_rs,
    const int* __restrict__ idx, int FiLog,
    const _Float16* __restrict__ Bw,
    const float* __restrict__ bias,
    void* __restrict__ Cp, u64 c_rs, int Mp_out,
    int M, int Np, int F, int flags, int ksp)   // flags: bit0 ELU, bit1 zeroLast
{
    constexpr int FM = TBM / WM / 16;
    constexpr int FF = TBF / WF / 16;
    constexpr int LPS_A = TBM / 64;
    constexpr bool BSM = (TBF < 64);
    constexpr int LPS_B = BSM ? 0 : TBF / 64;
    constexpr int LW0 = LPS_A + (BSM ? 1 : LPS_B);
    constexpr int LWX = LPS_A + LPS_B;
    constexpr int NI = (AMODE == 1) ? TBM : 2;

    __shared__ _Float16 sA[3][TBM][BK];
    __shared__ _Float16 sB[3][TBF][BK];
    __shared__ int sIdx[NI][9];

    const int t  = threadIdx.x;
    const int b  = blockIdx.z;
    const int m0 = blockIdx.y * TBM;
    const int f0 = blockIdx.x * TBF;
    const int lane = t & 63;
    const int wid  = t >> 6;
    const int wm = wid / WF;
    const int wf = wid % WF;
    const int lm = lane & 15;
    const int lg = lane >> 4;
    const int Fi = 1 << FiLog;

    f32x4 acc[FM][FF];
    #pragma unroll
    for (int i = 0; i < FM; ++i)
        #pragma unroll
        for (int j = 0; j < FF; ++j)
            acc[i][j] = (f32x4)0.0f;

    if constexpr (AMODE == 1) {
        for (int i = t; i < TBM * 9; i += 256) {
            int r = i / 9, k = i - r * 9;
            int rc = m0 + r; if (rc >= M) rc = M - 1;
            sIdx[r][k] = idx[rc * 9 + k];
        }
        __syncthreads();
    } else if constexpr (AMODE == 5) {
        if (t < 18) {
            int r = t / 9, k = t - r * 9;
            sIdx[r][k] = idx[((m0 >> 6) + r) * 9 + k];
        }
        __syncthreads();
    }

    auto stage = [&](int buf, int ks) {
        if constexpr (AMODE != 2) {
            #pragma unroll
            for (int j = 0; j < LPS_A; ++j) {
                int c   = t + j * 256;
                int row = c >> 2;
                int sw  = ((c & 3) ^ ((row >> 1) & 3)) * 8;   // pre-swizzled source chunk
                int col = ks * BK + sw;
                const _Float16* src;
                if constexpr (AMODE == 0 || AMODE == 3) {
                    int rc = m0 + row; if (rc >= M) rc = M - 1;
                    src = Aw + (u64)rc * Np + col;
                } else if constexpr (AMODE == 1) {
                    int k = col >> FiLog, fi = col & (Fi - 1);
                    src = Aw + (u64)sIdx[row][k] * a_rs + b * Fi + fi;
                } else if constexpr (AMODE == 4) {
                    int k = col >> FiLog, fi = col & (Fi - 1);
                    src = Aw + (u64)k * a_rs + (m0 + row) * Fi + fi;
                } else {  // 5
                    int k = col >> FiLog, fi = col & (Fi - 1);
                    int bb = (m0 + row) & 63;
                    src = Aw + (u64)sIdx[row >> 6][k] * a_rs + bb * Fi + fi;
                }
                gl16(src, &sA[buf][row][(c & 3) * 8]);   // linear dest
            }
        }
        if constexpr (!BSM) {
            #pragma unroll
            for (int j = 0; j < LPS_B; ++j) {
                int c   = t + j * 256;
                int row = c >> 2;
                int sw  = ((c & 3) ^ ((row >> 1) & 3)) * 8;
                gl16(Bw + (u64)(f0 + row) * Np + ks * BK + sw, &sB[buf][row][(c & 3) * 8]);
            }
        } else {
            if (wid == 0) {
                int c   = t;
                int row = c >> 2;
                int sw  = ((c & 3) ^ ((row >> 1) & 3)) * 8;
                gl16(Bw + (u64)(f0 + row) * Np + ks * BK + sw, &sB[buf][row][(c & 3) * 8]);
            }
        }
    };

    auto compute = [&](int buf) {
        const int sa = (lg ^ ((lm >> 1) & 3)) * 8;   // un-swizzle on read
        half8 af[FM], bf[FF];
        #pragma unroll
        for (int i = 0; i < FM; ++i)
            af[i] = *(const half8*)&sA[buf][wm * (FM * 16) + i * 16 + lm][sa];
        #pragma unroll
        for (int j = 0; j < FF; ++j)
            bf[j] = *(const half8*)&sB[buf][wf * (FF * 16) + j * 16 + lm][sa];
        #pragma unroll
        for (int i = 0; i < FM; ++i)
            #pragma unroll
            for (int j = 0; j < FF; ++j)
                acc[i][j] = __builtin_amdgcn_mfma_f32_16x16x32_f16(af[i], bf[j], acc[i][j], 0, 0, 0);
    };

    if constexpr (AMODE == 2) {
        stage(0, 0);   // B only
        {
            int row = t >> 1;
            int base = (t & 1) * 16;
            int rg = m0 + row;
            #pragma unroll
            for (int q = 0; q < 16; ++q) {
                int n = base + q;
                _Float16 val = (_Float16)0.f;
                if (rg < M && n < 27) {
                    int k = n / 3, fi = n - k * 3;
                    val = Aw[(u64)idx[rg * 9 + k] * a_rs + b * 3 + fi];
                }
                int ch = (n >> 3) ^ ((row >> 1) & 3);
                sA[0][row][ch * 8 + (n & 7)] = val;   // store swizzled
            }
        }
        __syncthreads();
        compute(0);
    } else {
        int kb = 0, ke = Np / BK;
        if constexpr (AMODE == 4) { kb = b * ksp; ke = kb + ksp; }
        stage(0, kb);
        if (kb + 1 < ke) stage(1, kb + 1);
        if (kb + 2 < ke) stage(2, kb + 2);
        int cur = 0;
        for (int ks = kb; ks < ke; ++ks) {
            int rem = ke - ks;
            if (rem >= 3) {
                if constexpr (LW0 == LWX) vwait<2 * LW0>();
                else { if (wid == 0) vwait<2 * LW0>(); else vwait<2 * LWX>(); }
            } else if (rem == 2) {
                if constexpr (LW0 == LWX) vwait<LW0>();
                else { if (wid == 0) vwait<LW0>(); else vwait<LWX>(); }
            } else {
                vwait<0>();
            }
            barx();
            compute(cur);
            barx();
            if (ks + 3 < ke) stage(cur, ks + 3);
            cur = (cur == 2) ? 0 : cur + 1;
        }
    }

    #pragma unroll
    for (int j = 0; j < FF; ++j) {
        int fl = f0 + wf * (FF * 16) + j * 16 + lm;
        float bv = 0.f;
        if (bias != nullptr && fl < F) bv = bias[fl];
        #pragma unroll
        for (int i = 0; i < FM; ++i) {
            #pragma unroll
            for (int r = 0; r < 4; ++r) {
                int m = m0 + wm * (FM * 16) + i * 16 + lg * 4 + r;
                float v = acc[i][j][r] + bv;
                if (flags & 1) v = (v > 0.f) ? v : expm1f(v);
                if constexpr (EPI == EPI_NAT) {
                    if (m < M && fl < F)
                        ((_Float16*)Cp)[(u64)m * c_rs + fl] = (_Float16)v;
                } else if constexpr (EPI == EPI_TR) {
                    if (m < Mp_out && fl < F) {
                        float o = (m < M && !((flags & 2) && m == M - 1)) ? v : 0.f;
                        ((_Float16*)Cp)[(u64)b * c_rs + (u64)fl * Mp_out + m] = (_Float16)o;
                    }
                } else if constexpr (EPI == EPI_FCD) {
                    if (m < M && fl < F)
                        ((_Float16*)Cp)[((u64)m * 256 + (fl & 255)) * 32 + (fl >> 8)] = (_Float16)v;
                } else if constexpr (EPI == EPI_PART) {
                    if (m < M && fl < F)
                        ((float*)Cp)[(u64)b * c_rs + (u64)m * F + fl] = v;
                } else {  // EPI_OUT (rows folded: m = v*64+b)
                    if (m < M && fl < F) {
                        int vo = m >> 6, bb = m & 63;
                        float o = ((flags & 2) && vo == Mp_out - 1) ? 0.f : v;
                        ((float*)Cp)[((u64)bb * Mp_out + vo) * 3 + fl] = o;
                    }
                }
            }
        }
    }
}

// ---- fused weight conversion ----
struct CvtPtrs { const float* p[18]; };

constexpr int CV_R[18]  = {1257,5024,315,1257,80,315,21,80,  64,64,128,256,256,5376,128,64,64,16};
constexpr int CV_N[18]  = {5024,1257,1257,315,315,80,80,21,  27,576,576,1152,5376,256,2304,1152,576,576};
constexpr int CV_NP[18] = {5120,1280,1280,320,320,96,96,32,  32,576,576,1152,5376,256,2304,1152,576,576};
constexpr int CV_F[18]  = {0,0,0,0,0,0,0,0,  64,64,128,256,256,5376,128,64,64,3};

constexpr u64 cv_elems(int i) { return (u64)CV_R[i] * CV_NP[i]; }
constexpr u64 cv_off(int i) { u64 o = 0; for (int j = 0; j < i; ++j) o += (cv_elems(j) + 255) & ~(u64)255; return o; }
constexpr int cv_blk(int i) { return (int)((cv_elems(i) + 255) >> 8); }
constexpr int cv_start(int i) { int s = 0; for (int j = 0; j < i; ++j) s += cv_blk(j); return s; }

__global__ __launch_bounds__(256) void cvt_all(CvtPtrs ps, _Float16* __restrict__ dst)
{
    const int bx = blockIdx.x, t = threadIdx.x;
    #pragma unroll
    for (int i = 0; i < 18; ++i) {
        if (bx >= cv_start(i) && bx < cv_start(i + 1)) {
            const u64 e = (u64)(bx - cv_start(i)) * 256 + t;
            if (e < cv_elems(i)) {
                const int NP = CV_NP[i], N = CV_N[i], Fo = CV_F[i];
                int row = (int)(e / (u64)NP);
                int col = (int)(e - (u64)row * NP);
                float v = 0.f;
                const float* s = ps.p[i];
                if (Fo == 0) { if (col < N) v = s[(u64)row * N + col]; }
                else         { if (col < N && row < Fo) v = s[(u64)col * Fo + row]; }
                dst[cv_off(i) + e] = (_Float16)v;
            }
        }
    }
}

__global__ void cvt_x(const float* __restrict__ src, _Float16* __restrict__ dst)
{
    int i = blockIdx.x * 256 + threadIdx.x;
    if (i >= 64 * 5024 * 3) return;
    int v = i / 192;
    int r = i - v * 192;
    int b = r / 3, c = r - b * 3;
    dst[i] = (_Float16)src[((u64)b * 5024 + v) * 3 + c];
}

__global__ void reduce_fce(const float* __restrict__ part, const float* __restrict__ bias,
                           _Float16* __restrict__ z)
{
    int i = blockIdx.x * 256 + threadIdx.x;  // 64*256
    int fl = i & 255;
    float s = bias[fl];
    #pragma unroll
    for (int p = 0; p < 8; ++p) s += part[(u64)p * 16384 + i];
    z[i] = (_Float16)s;
}

extern "C" void kernel_launch(void* const* d_in, const int* in_sizes, int n_in,
                              void* d_out, int out_size, void* d_ws, size_t ws_size,
                              hipStream_t stream)
{
    const float* x  = (const float*)d_in[0];
    const int* s0 = (const int*)d_in[1];
    const int* s1 = (const int*)d_in[2];
    const int* s2 = (const int*)d_in[3];
    const int* s3 = (const int*)d_in[4];
    const float* be0 = (const float*)d_in[14];
    const float* be1 = (const float*)d_in[16];
    const float* be2 = (const float*)d_in[18];
    const float* be3 = (const float*)d_in[20];
    const float* fceb = (const float*)d_in[22];
    const float* fcdb = (const float*)d_in[24];
    const float* bd0 = (const float*)d_in[26];
    const float* bd1 = (const float*)d_in[28];
    const float* bd2 = (const float*)d_in[30];
    const float* bd3 = (const float*)d_in[32];

    _Float16* W = (_Float16*)d_ws;
    size_t off = 0;
    auto alloc = [&](size_t e) { size_t o = off; off += (e + 255) & ~(size_t)255; return o; };

    const size_t oActV = alloc((size_t)5024 * 4096);   // [vertex][(b,f)]
    const size_t oActT = alloc((size_t)4096 * 5120);   // [(b,f)][vertex_padded]
    const size_t oZ    = alloc((size_t)64 * 256);
    const size_t oPart = alloc((size_t)8 * 64 * 256 * 2);  // fp32 partials
    const size_t oU3in = alloc((size_t)16384 * 32);
    const size_t oXp   = alloc((size_t)5024 * 192);
    const size_t oCvt  = alloc((size_t)(cv_off(17) + ((cv_elems(17) + 255) & ~(u64)255)));
    auto wofs = [&](int i) { return oCvt + (size_t)cv_off(i); };

    // ---- conversions ----
    cvt_x<<<dim3((64 * 5024 * 3 + 255) / 256), 256, 0, stream>>>(x, W + oXp);
    {
        CvtPtrs ps;
        ps.p[0] = (const float*)d_in[5];   // D0
        ps.p[1] = (const float*)d_in[6];   // U0
        ps.p[2] = (const float*)d_in[7];   // D1
        ps.p[3] = (const float*)d_in[8];   // U1
        ps.p[4] = (const float*)d_in[9];   // D2
        ps.p[5] = (const float*)d_in[10];  // U2
        ps.p[6] = (const float*)d_in[11];  // D3
        ps.p[7] = (const float*)d_in[12];  // U3
        ps.p[8] = (const float*)d_in[13];  // We0
        ps.p[9] = (const float*)d_in[15];  // We1
        ps.p[10] = (const float*)d_in[17]; // We2
        ps.p[11] = (const float*)d_in[19]; // We3
        ps.p[12] = (const float*)d_in[21]; // fceW
        ps.p[13] = (const float*)d_in[23]; // fcdW
        ps.p[14] = (const float*)d_in[25]; // Wd0
        ps.p[15] = (const float*)d_in[27]; // Wd1
        ps.p[16] = (const float*)d_in[29]; // Wd2
        ps.p[17] = (const float*)d_in[31]; // Wd3
        cvt_all<<<dim3(cv_start(18)), 256, 0, stream>>>(ps, W + oCvt);
    }
    hipMemsetAsync(W + oU3in, 0, (size_t)16384 * 32 * sizeof(_Float16), stream);

    #define GEMM(AM, EP, BM_, BF_, WM_, WF_, gx, gy, gz, Aw_, ars_, idx_, FiL_, Bw_, bias_, Cp_, crs_, Mp_, M_, Np_, F_, fl_, ksp_) \
        gemm_k<AM, EP, BM_, BF_, WM_, WF_><<<dim3(gx, gy, gz), 256, 0, stream>>>( \
            Aw_, ars_, idx_, FiL_, Bw_, bias_, Cp_, crs_, Mp_, M_, Np_, F_, fl_, ksp_)

    // ---- encoder ----
    GEMM(2, EPI_TR, 128, 64, 2, 2, 1, 40, 64, W + oXp, 192, s0, 0,
         W + wofs(8), be0, W + oActT, (u64)64 * 5120, 5120, 5024, 32, 64, 3, 0);
    pool_k<128><<<dim3(16, 10), 512, 0, stream>>>(
        W + wofs(0), W + oActT, W + oActV, 1257, 5120, 4096);
    GEMM(1, EPI_TR, 128, 64, 2, 2, 1, 10, 64, W + oActV, 4096, s1, 6,
         W + wofs(9), be1, W + oActT, (u64)64 * 1280, 1280, 1257, 576, 64, 3, 0);
    GEMM(0, EPI_NAT, 64, 128, 2, 2, 32, 5, 1, W + wofs(2), 0, nullptr, 0,
         W + oActT, nullptr, W + oActV, 4096, 0, 315, 1280, 4096, 0, 0);
    GEMM(1, EPI_TR, 128, 64, 2, 2, 2, 3, 64, W + oActV, 4096, s2, 6,
         W + wofs(10), be2, W + oActT, (u64)128 * 320, 320, 315, 576, 128, 3, 0);
    GEMM(0, EPI_NAT, 64, 128, 2, 2, 64, 2, 1, W + wofs(4), 0, nullptr, 0,
         W + oActT, nullptr, W + oActV, 8192, 0, 80, 320, 8192, 0, 0);
    GEMM(1, EPI_TR, 128, 64, 2, 2, 4, 1, 64, W + oActV, 8192, s3, 7,
         W + wofs(11), be3, W + oActT, (u64)256 * 96, 96, 80, 1152, 256, 3, 0);
    GEMM(0, EPI_NAT, 64, 128, 2, 2, 128, 1, 1, W + wofs(6), 0, nullptr, 0,
         W + oActT, nullptr, W + oActV, 16384, 0, 21, 96, 16384, 0, 0);
    // ---- bottleneck ----
    GEMM(4, EPI_PART, 64, 64, 2, 2, 4, 1, 8, W + oActV, 16384, nullptr, 8,
         W + wofs(12), nullptr, W + oPart, (u64)64 * 256, 0, 64, 5376, 256, 0, 21);
    reduce_fce<<<dim3(64), 256, 0, stream>>>((const float*)(W + oPart), fceb, W + oZ);
    GEMM(3, EPI_FCD, 64, 128, 2, 2, 42, 1, 1, W + oZ, 0, nullptr, 0,
         W + wofs(13), fcdb, W + oU3in, 0, 0, 64, 256, 5376, 0, 0);
    // ---- decoder ----
    GEMM(0, EPI_NAT, 64, 128, 2, 2, 128, 2, 1, W + wofs(7), 0, nullptr, 0,
         W + oU3in, nullptr, W + oActV, 16384, 0, 80, 32, 16384, 0, 0);
    GEMM(1, EPI_TR, 128, 64, 2, 2, 2, 1, 64, W + oActV, 16384, s3, 8,
         W + wofs(14), bd0, W + oActT, (u64)128 * 96, 96, 80, 2304, 128, 3, 0);
    GEMM(0, EPI_NAT, 64, 128, 2, 2, 64, 5, 1, W + wofs(5), 0, nullptr, 0,
         W + oActT, nullptr, W + oActV, 8192, 0, 315, 96, 8192, 0, 0);
    GEMM(1, EPI_TR, 128, 64, 2, 2, 1, 3, 64, W + oActV, 8192, s2, 7,
         W + wofs(15), bd1, W + oActT, (u64)64 * 320, 320, 315, 1152, 64, 3, 0);
    pool_k<128><<<dim3(16, 10), 512, 0, stream>>>(
        W + wofs(3), W + oActT, W + oActV, 1257, 320, 4096);
    GEMM(1, EPI_TR, 128, 64, 2, 2, 1, 10, 64, W + oActV, 4096, s1, 6,
         W + wofs(16), bd2, W + oActT, (u64)64 * 1280, 1280, 1257, 576, 64, 3, 0);
    pool_k<256><<<dim3(16, 20), 512, 0, stream>>>(
        W + wofs(1), W + oActT, W + oActV, 5024, 1280, 4096);
    GEMM(5, EPI_OUT, 128, 16, 4, 1, 1, 2512, 1, W + oActV, 4096, s0, 6,
         W + wofs(17), bd3, d_out, 0, 5024, 321536, 576, 3, 2, 0);
    #undef GEMM
}

// Round 8
// 594.814 us; speedup vs baseline: 8.1660x; 1.0434x over previous
//
#include <hip/hip_runtime.h>
#include <math.h>

typedef __attribute__((ext_vector_type(8))) _Float16 half8;
typedef __attribute__((ext_vector_type(4))) float f32x4;
typedef unsigned long long u64;

#define BK 32

#define EPI_NAT  0
#define EPI_TR   1
#define EPI_FCD  2
#define EPI_OUT  3
#define EPI_PART 4

typedef const __attribute__((address_space(1))) void* gas1;
typedef __attribute__((address_space(3))) void* las3;

__device__ __forceinline__ void gl16(const void* g, void* l) {
    __builtin_amdgcn_global_load_lds((gas1)g, (las3)l, 16, 0, 0);
}
template<int N> __device__ __forceinline__ void vwait() {
    asm volatile("s_waitcnt vmcnt(%0)" :: "n"(N) : "memory");
}
__device__ __forceinline__ void barx() {
    asm volatile("" ::: "memory");
    __builtin_amdgcn_s_barrier();
    asm volatile("" ::: "memory");
}

// ============ unified pool kernel: 256 thr, 4 waves, 128x128 tile, BK=32 ============
// A [M][Np] fp16 (rows clamped), B [cols][Np] fp16 (actT layout), C [M][cols] fp16
// 3 blocks/CU co-resident: cross-block overlap hides load latency + barrier drains.
__global__ __launch_bounds__(256, 3) void pool2_k(
    const _Float16* __restrict__ Aw, const _Float16* __restrict__ Bw,
    _Float16* __restrict__ Cp, int M, int Np, u64 c_rs)
{
    __shared__ _Float16 sA[2][128][BK];
    __shared__ _Float16 sB[2][128][BK];

    const int t  = threadIdx.x;
    const int m0 = blockIdx.y * 128;
    const int f0 = blockIdx.x * 128;
    const int lane = t & 63;
    const int wid  = t >> 6;
    const int wm = wid >> 1;     // 0..1
    const int wf = wid & 1;      // 0..1
    const int lm = lane & 15;
    const int lg = lane >> 4;

    f32x4 acc[4][4];
    #pragma unroll
    for (int i = 0; i < 4; ++i)
        #pragma unroll
        for (int j = 0; j < 4; ++j)
            acc[i][j] = (f32x4)0.0f;

    auto stage = [&](int buf, int ks) {
        #pragma unroll
        for (int j = 0; j < 2; ++j) {
            int c   = t + j * 256;
            int row = c >> 2;
            int sw  = ((c & 3) ^ ((row >> 1) & 3)) * 8;   // pre-swizzled source chunk
            int rc  = m0 + row; if (rc >= M) rc = M - 1;
            gl16(Aw + (u64)rc * Np + ks * BK + sw,
                 (_Float16*)&sA[buf][0][0] + (u64)c * 8);  // linear dest
        }
        #pragma unroll
        for (int j = 0; j < 2; ++j) {
            int c   = t + j * 256;
            int row = c >> 2;
            int sw  = ((c & 3) ^ ((row >> 1) & 3)) * 8;
            gl16(Bw + (u64)(f0 + row) * Np + ks * BK + sw,
                 (_Float16*)&sB[buf][0][0] + (u64)c * 8);
        }
    };

    auto compute = [&](int buf) {
        const int sa = (lg ^ ((lm >> 1) & 3)) * 8;        // un-swizzle on read
        half8 af[4], bf[4];
        #pragma unroll
        for (int i = 0; i < 4; ++i)
            af[i] = *(const half8*)&sA[buf][wm * 64 + i * 16 + lm][sa];
        #pragma unroll
        for (int j = 0; j < 4; ++j)
            bf[j] = *(const half8*)&sB[buf][wf * 64 + j * 16 + lm][sa];
        #pragma unroll
        for (int i = 0; i < 4; ++i)
            #pragma unroll
            for (int j = 0; j < 4; ++j)
                acc[i][j] = __builtin_amdgcn_mfma_f32_16x16x32_f16(af[i], bf[j], acc[i][j], 0, 0, 0);
    };

    const int ke = Np / BK;
    stage(0, 0);
    int cur = 0;
    for (int ks = 0; ks < ke; ++ks) {
        if (ks + 1 < ke) { stage(cur ^ 1, ks + 1); vwait<4>(); }
        else             { vwait<0>(); }
        barx();
        compute(cur);
        barx();
        cur ^= 1;
    }

    #pragma unroll
    for (int j = 0; j < 4; ++j) {
        int fl = f0 + wf * 64 + j * 16 + lm;
        #pragma unroll
        for (int i = 0; i < 4; ++i) {
            #pragma unroll
            for (int r = 0; r < 4; ++r) {
                int m = m0 + wm * 64 + i * 16 + lg * 4 + r;
                if (m < M)
                    Cp[(u64)m * c_rs + fl] = (_Float16)acc[i][j][r];
            }
        }
    }
}

// ============ general kernel (sconv / fc) ============
// AMODE: 1 sconv gather (idx via LDS), 2 sconv0 (Fi=3, nk=1),
//        3 fc, 4 fc-enc split-K, 5 sconv rows-folded [Wd3]
template<int AMODE, int EPI, int TBM, int TBF, int WM, int WF>
__global__ __launch_bounds__(256) void gemm_k(
    const _Float16* __restrict__ Aw, u64 a_rs,
    const int* __restrict__ idx, int FiLog,
    const _Float16* __restrict__ Bw,
    const float* __restrict__ bias,
    void* __restrict__ Cp, u64 c_rs, int Mp_out,
    int M, int Np, int F, int flags, int ksp)   // flags: bit0 ELU, bit1 zeroLast
{
    constexpr int FM = TBM / WM / 16;
    constexpr int FF = TBF / WF / 16;
    constexpr int LPS_A = TBM / 64;
    constexpr bool BSM = (TBF < 64);
    constexpr int LPS_B = BSM ? 0 : TBF / 64;
    constexpr int LW0 = LPS_A + (BSM ? 1 : LPS_B);
    constexpr int LWX = LPS_A + LPS_B;
    constexpr int NI = (AMODE == 1) ? TBM : 2;

    __shared__ _Float16 sA[3][TBM][BK];
    __shared__ _Float16 sB[3][TBF][BK];
    __shared__ int sIdx[NI][9];

    const int t  = threadIdx.x;
    const int b  = blockIdx.z;
    const int m0 = blockIdx.y * TBM;
    const int f0 = blockIdx.x * TBF;
    const int lane = t & 63;
    const int wid  = t >> 6;
    const int wm = wid / WF;
    const int wf = wid % WF;
    const int lm = lane & 15;
    const int lg = lane >> 4;
    const int Fi = 1 << FiLog;

    f32x4 acc[FM][FF];
    #pragma unroll
    for (int i = 0; i < FM; ++i)
        #pragma unroll
        for (int j = 0; j < FF; ++j)
            acc[i][j] = (f32x4)0.0f;

    if constexpr (AMODE == 1) {
        for (int i = t; i < TBM * 9; i += 256) {
            int r = i / 9, k = i - r * 9;
            int rc = m0 + r; if (rc >= M) rc = M - 1;
            sIdx[r][k] = idx[rc * 9 + k];
        }
        __syncthreads();
    } else if constexpr (AMODE == 5) {
        if (t < 18) {
            int r = t / 9, k = t - r * 9;
            sIdx[r][k] = idx[((m0 >> 6) + r) * 9 + k];
        }
        __syncthreads();
    }

    auto stage = [&](int buf, int ks) {
        if constexpr (AMODE != 2) {
            #pragma unroll
            for (int j = 0; j < LPS_A; ++j) {
                int c   = t + j * 256;
                int row = c >> 2;
                int sw  = ((c & 3) ^ ((row >> 1) & 3)) * 8;   // pre-swizzled source chunk
                int col = ks * BK + sw;
                const _Float16* src;
                if constexpr (AMODE == 3) {
                    int rc = m0 + row; if (rc >= M) rc = M - 1;
                    src = Aw + (u64)rc * Np + col;
                } else if constexpr (AMODE == 1) {
                    int k = col >> FiLog, fi = col & (Fi - 1);
                    src = Aw + (u64)sIdx[row][k] * a_rs + b * Fi + fi;
                } else if constexpr (AMODE == 4) {
                    int k = col >> FiLog, fi = col & (Fi - 1);
                    src = Aw + (u64)k * a_rs + (m0 + row) * Fi + fi;
                } else {  // 5
                    int k = col >> FiLog, fi = col & (Fi - 1);
                    int bb = (m0 + row) & 63;
                    src = Aw + (u64)sIdx[row >> 6][k] * a_rs + bb * Fi + fi;
                }
                gl16(src, &sA[buf][row][(c & 3) * 8]);   // linear dest
            }
        }
        if constexpr (!BSM) {
            #pragma unroll
            for (int j = 0; j < LPS_B; ++j) {
                int c   = t + j * 256;
                int row = c >> 2;
                int sw  = ((c & 3) ^ ((row >> 1) & 3)) * 8;
                gl16(Bw + (u64)(f0 + row) * Np + ks * BK + sw, &sB[buf][row][(c & 3) * 8]);
            }
        } else {
            if (wid == 0) {
                int c   = t;
                int row = c >> 2;
                int sw  = ((c & 3) ^ ((row >> 1) & 3)) * 8;
                gl16(Bw + (u64)(f0 + row) * Np + ks * BK + sw, &sB[buf][row][(c & 3) * 8]);
            }
        }
    };

    auto compute = [&](int buf) {
        const int sa = (lg ^ ((lm >> 1) & 3)) * 8;   // un-swizzle on read
        half8 af[FM], bf[FF];
        #pragma unroll
        for (int i = 0; i < FM; ++i)
            af[i] = *(const half8*)&sA[buf][wm * (FM * 16) + i * 16 + lm][sa];
        #pragma unroll
        for (int j = 0; j < FF; ++j)
            bf[j] = *(const half8*)&sB[buf][wf * (FF * 16) + j * 16 + lm][sa];
        #pragma unroll
        for (int i = 0; i < FM; ++i)
            #pragma unroll
            for (int j = 0; j < FF; ++j)
                acc[i][j] = __builtin_amdgcn_mfma_f32_16x16x32_f16(af[i], bf[j], acc[i][j], 0, 0, 0);
    };

    if constexpr (AMODE == 2) {
        stage(0, 0);   // B only
        {
            int row = t >> 1;
            int base = (t & 1) * 16;
            int rg = m0 + row;
            #pragma unroll
            for (int q = 0; q < 16; ++q) {
                int n = base + q;
                _Float16 val = (_Float16)0.f;
                if (rg < M && n < 27) {
                    int k = n / 3, fi = n - k * 3;
                    val = Aw[(u64)idx[rg * 9 + k] * a_rs + b * 3 + fi];
                }
                int ch = (n >> 3) ^ ((row >> 1) & 3);
                sA[0][row][ch * 8 + (n & 7)] = val;   // store swizzled
            }
        }
        __syncthreads();
        compute(0);
    } else {
        int kb = 0, ke = Np / BK;
        if constexpr (AMODE == 4) { kb = b * ksp; ke = kb + ksp; }
        stage(0, kb);
        if (kb + 1 < ke) stage(1, kb + 1);
        if (kb + 2 < ke) stage(2, kb + 2);
        int cur = 0;
        for (int ks = kb; ks < ke; ++ks) {
            int rem = ke - ks;
            if (rem >= 3) {
                if constexpr (LW0 == LWX) vwait<2 * LW0>();
                else { if (wid == 0) vwait<2 * LW0>(); else vwait<2 * LWX>(); }
            } else if (rem == 2) {
                if constexpr (LW0 == LWX) vwait<LW0>();
                else { if (wid == 0) vwait<LW0>(); else vwait<LWX>(); }
            } else {
                vwait<0>();
            }
            barx();
            compute(cur);
            barx();
            if (ks + 3 < ke) stage(cur, ks + 3);
            cur = (cur == 2) ? 0 : cur + 1;
        }
    }

    #pragma unroll
    for (int j = 0; j < FF; ++j) {
        int fl = f0 + wf * (FF * 16) + j * 16 + lm;
        float bv = 0.f;
        if (bias != nullptr && fl < F) bv = bias[fl];
        #pragma unroll
        for (int i = 0; i < FM; ++i) {
            #pragma unroll
            for (int r = 0; r < 4; ++r) {
                int m = m0 + wm * (FM * 16) + i * 16 + lg * 4 + r;
                float v = acc[i][j][r] + bv;
                if (flags & 1) v = (v > 0.f) ? v : expm1f(v);
                if constexpr (EPI == EPI_NAT) {
                    if (m < M && fl < F)
                        ((_Float16*)Cp)[(u64)m * c_rs + fl] = (_Float16)v;
                } else if constexpr (EPI == EPI_TR) {
                    if (m < Mp_out && fl < F) {
                        float o = (m < M && !((flags & 2) && m == M - 1)) ? v : 0.f;
                        ((_Float16*)Cp)[(u64)b * c_rs + (u64)fl * Mp_out + m] = (_Float16)o;
                    }
                } else if constexpr (EPI == EPI_FCD) {
                    if (m < M && fl < F)
                        ((_Float16*)Cp)[((u64)m * 256 + (fl & 255)) * 32 + (fl >> 8)] = (_Float16)v;
                } else if constexpr (EPI == EPI_PART) {
                    if (m < M && fl < F)
                        ((float*)Cp)[(u64)b * c_rs + (u64)m * F + fl] = v;
                } else {  // EPI_OUT (rows folded: m = v*64+b)
                    if (m < M && fl < F) {
                        int vo = m >> 6, bb = m & 63;
                        float o = ((flags & 2) && vo == Mp_out - 1) ? 0.f : v;
                        ((float*)Cp)[((u64)bb * Mp_out + vo) * 3 + fl] = o;
                    }
                }
            }
        }
    }
}

// ---- fused weight conversion ----
struct CvtPtrs { const float* p[18]; };

constexpr int CV_R[18]  = {1257,5024,315,1257,80,315,21,80,  64,64,128,256,256,5376,128,64,64,16};
constexpr int CV_N[18]  = {5024,1257,1257,315,315,80,80,21,  27,576,576,1152,5376,256,2304,1152,576,576};
constexpr int CV_NP[18] = {5120,1280,1280,320,320,96,96,32,  32,576,576,1152,5376,256,2304,1152,576,576};
constexpr int CV_F[18]  = {0,0,0,0,0,0,0,0,  64,64,128,256,256,5376,128,64,64,3};

constexpr u64 cv_elems(int i) { return (u64)CV_R[i] * CV_NP[i]; }
constexpr u64 cv_off(int i) { u64 o = 0; for (int j = 0; j < i; ++j) o += (cv_elems(j) + 255) & ~(u64)255; return o; }
constexpr int cv_blk(int i) { return (int)((cv_elems(i) + 255) >> 8); }
constexpr int cv_start(int i) { int s = 0; for (int j = 0; j < i; ++j) s += cv_blk(j); return s; }

__global__ __launch_bounds__(256) void cvt_all(CvtPtrs ps, _Float16* __restrict__ dst)
{
    const int bx = blockIdx.x, t = threadIdx.x;
    #pragma unroll
    for (int i = 0; i < 18; ++i) {
        if (bx >= cv_start(i) && bx < cv_start(i + 1)) {
            const u64 e = (u64)(bx - cv_start(i)) * 256 + t;
            if (e < cv_elems(i)) {
                const int NP = CV_NP[i], N = CV_N[i], Fo = CV_F[i];
                int row = (int)(e / (u64)NP);
                int col = (int)(e - (u64)row * NP);
                float v = 0.f;
                const float* s = ps.p[i];
                if (Fo == 0) { if (col < N) v = s[(u64)row * N + col]; }
                else         { if (col < N && row < Fo) v = s[(u64)col * Fo + row]; }
                dst[cv_off(i) + e] = (_Float16)v;
            }
        }
    }
}

__global__ void cvt_x(const float* __restrict__ src, _Float16* __restrict__ dst)
{
    int i = blockIdx.x * 256 + threadIdx.x;
    if (i >= 64 * 5024 * 3) return;
    int v = i / 192;
    int r = i - v * 192;
    int b = r / 3, c = r - b * 3;
    dst[i] = (_Float16)src[((u64)b * 5024 + v) * 3 + c];
}

__global__ void reduce_fce(const float* __restrict__ part, const float* __restrict__ bias,
                           _Float16* __restrict__ z)
{
    int i = blockIdx.x * 256 + threadIdx.x;  // 64*256
    int fl = i & 255;
    float s = bias[fl];
    #pragma unroll
    for (int p = 0; p < 8; ++p) s += part[(u64)p * 16384 + i];
    z[i] = (_Float16)s;
}

extern "C" void kernel_launch(void* const* d_in, const int* in_sizes, int n_in,
                              void* d_out, int out_size, void* d_ws, size_t ws_size,
                              hipStream_t stream)
{
    const float* x  = (const float*)d_in[0];
    const int* s0 = (const int*)d_in[1];
    const int* s1 = (const int*)d_in[2];
    const int* s2 = (const int*)d_in[3];
    const int* s3 = (const int*)d_in[4];
    const float* be0 = (const float*)d_in[14];
    const float* be1 = (const float*)d_in[16];
    const float* be2 = (const float*)d_in[18];
    const float* be3 = (const float*)d_in[20];
    const float* fceb = (const float*)d_in[22];
    const float* fcdb = (const float*)d_in[24];
    const float* bd0 = (const float*)d_in[26];
    const float* bd1 = (const float*)d_in[28];
    const float* bd2 = (const float*)d_in[30];
    const float* bd3 = (const float*)d_in[32];

    _Float16* W = (_Float16*)d_ws;
    size_t off = 0;
    auto alloc = [&](size_t e) { size_t o = off; off += (e + 255) & ~(size_t)255; return o; };

    const size_t oActV = alloc((size_t)5024 * 4096);   // [vertex][(b,f)]
    const size_t oActT = alloc((size_t)4096 * 5120);   // [(b,f)][vertex_padded]
    const size_t oZ    = alloc((size_t)64 * 256);
    const size_t oPart = alloc((size_t)8 * 64 * 256 * 2);  // fp32 partials
    const size_t oU3in = alloc((size_t)16384 * 32);
    const size_t oXp   = alloc((size_t)5024 * 192);
    const size_t oCvt  = alloc((size_t)(cv_off(17) + ((cv_elems(17) + 255) & ~(u64)255)));
    auto wofs = [&](int i) { return oCvt + (size_t)cv_off(i); };

    // ---- conversions ----
    cvt_x<<<dim3((64 * 5024 * 3 + 255) / 256), 256, 0, stream>>>(x, W + oXp);
    {
        CvtPtrs ps;
        ps.p[0] = (const float*)d_in[5];   // D0
        ps.p[1] = (const float*)d_in[6];   // U0
        ps.p[2] = (const float*)d_in[7];   // D1
        ps.p[3] = (const float*)d_in[8];   // U1
        ps.p[4] = (const float*)d_in[9];   // D2
        ps.p[5] = (const float*)d_in[10];  // U2
        ps.p[6] = (const float*)d_in[11];  // D3
        ps.p[7] = (const float*)d_in[12];  // U3
        ps.p[8] = (const float*)d_in[13];  // We0
        ps.p[9] = (const float*)d_in[15];  // We1
        ps.p[10] = (const float*)d_in[17]; // We2
        ps.p[11] = (const float*)d_in[19]; // We3
        ps.p[12] = (const float*)d_in[21]; // fceW
        ps.p[13] = (const float*)d_in[23]; // fcdW
        ps.p[14] = (const float*)d_in[25]; // Wd0
        ps.p[15] = (const float*)d_in[27]; // Wd1
        ps.p[16] = (const float*)d_in[29]; // Wd2
        ps.p[17] = (const float*)d_in[31]; // Wd3
        cvt_all<<<dim3(cv_start(18)), 256, 0, stream>>>(ps, W + oCvt);
    }
    hipMemsetAsync(W + oU3in, 0, (size_t)16384 * 32 * sizeof(_Float16), stream);

    #define GEMM(AM, EP, BM_, BF_, WM_, WF_, gx, gy, gz, Aw_, ars_, idx_, FiL_, Bw_, bias_, Cp_, crs_, Mp_, M_, Np_, F_, fl_, ksp_) \
        gemm_k<AM, EP, BM_, BF_, WM_, WF_><<<dim3(gx, gy, gz), 256, 0, stream>>>( \
            Aw_, ars_, idx_, FiL_, Bw_, bias_, Cp_, crs_, Mp_, M_, Np_, F_, fl_, ksp_)
    #define POOL(gx, gy, Aw_, Bw_, Cp_, M_, Np_, crs_) \
        pool2_k<<<dim3(gx, gy), 256, 0, stream>>>(Aw_, Bw_, Cp_, M_, Np_, crs_)

    // ---- encoder ----
    GEMM(2, EPI_TR, 128, 64, 2, 2, 1, 40, 64, W + oXp, 192, s0, 0,
         W + wofs(8), be0, W + oActT, (u64)64 * 5120, 5120, 5024, 32, 64, 3, 0);
    POOL(32, 10, W + wofs(0), W + oActT, W + oActV, 1257, 5120, 4096);
    GEMM(1, EPI_TR, 128, 64, 2, 2, 1, 10, 64, W + oActV, 4096, s1, 6,
         W + wofs(9), be1, W + oActT, (u64)64 * 1280, 1280, 1257, 576, 64, 3, 0);
    POOL(32, 3, W + wofs(2), W + oActT, W + oActV, 315, 1280, 4096);
    GEMM(1, EPI_TR, 128, 64, 2, 2, 2, 3, 64, W + oActV, 4096, s2, 6,
         W + wofs(10), be2, W + oActT, (u64)128 * 320, 320, 315, 576, 128, 3, 0);
    POOL(64, 1, W + wofs(4), W + oActT, W + oActV, 80, 320, 8192);
    GEMM(1, EPI_TR, 128, 64, 2, 2, 4, 1, 64, W + oActV, 8192, s3, 7,
         W + wofs(11), be3, W + oActT, (u64)256 * 96, 96, 80, 1152, 256, 3, 0);
    POOL(128, 1, W + wofs(6), W + oActT, W + oActV, 21, 96, 16384);
    // ---- bottleneck ----
    GEMM(4, EPI_PART, 64, 64, 2, 2, 4, 1, 8, W + oActV, 16384, nullptr, 8,
         W + wofs(12), nullptr, W + oPart, (u64)64 * 256, 0, 64, 5376, 256, 0, 21);
    reduce_fce<<<dim3(64), 256, 0, stream>>>((const float*)(W + oPart), fceb, W + oZ);
    GEMM(3, EPI_FCD, 64, 128, 2, 2, 42, 1, 1, W + oZ, 0, nullptr, 0,
         W + wofs(13), fcdb, W + oU3in, 0, 0, 64, 256, 5376, 0, 0);
    // ---- decoder ----
    POOL(128, 1, W + wofs(7), W + oU3in, W + oActV, 80, 32, 16384);
    GEMM(1, EPI_TR, 128, 64, 2, 2, 2, 1, 64, W + oActV, 16384, s3, 8,
         W + wofs(14), bd0, W + oActT, (u64)128 * 96, 96, 80, 2304, 128, 3, 0);
    POOL(64, 3, W + wofs(5), W + oActT, W + oActV, 315, 96, 8192);
    GEMM(1, EPI_TR, 128, 64, 2, 2, 1, 3, 64, W + oActV, 8192, s2, 7,
         W + wofs(15), bd1, W + oActT, (u64)64 * 320, 320, 315, 1152, 64, 3, 0);
    POOL(32, 10, W + wofs(3), W + oActT, W + oActV, 1257, 320, 4096);
    GEMM(1, EPI_TR, 128, 64, 2, 2, 1, 10, 64, W + oActV, 4096, s1, 6,
         W + wofs(16), bd2, W + oActT, (u64)64 * 1280, 1280, 1257, 576, 64, 3, 0);
    POOL(32, 40, W + wofs(1), W + oActT, W + oActV, 5024, 1280, 4096);
    GEMM(5, EPI_OUT, 128, 16, 4, 1, 1, 2512, 1, W + oActV, 4096, s0, 6,
         W + wofs(17), bd3, d_out, 0, 5024, 321536, 576, 3, 2, 0);
    #undef GEMM
    #undef POOL
}

// Round 9
// 572.155 us; speedup vs baseline: 8.4894x; 1.0396x over previous
//
#include <hip/hip_runtime.h>
#include <math.h>

typedef __attribute__((ext_vector_type(8))) _Float16 half8;
typedef __attribute__((ext_vector_type(4))) float f32x4;
typedef unsigned long long u64;

#define BK 32

#define EPI_NAT  0
#define EPI_TR   1
#define EPI_FCD  2
#define EPI_OUT  3
#define EPI_PART 4

typedef const __attribute__((address_space(1))) void* gas1;
typedef __attribute__((address_space(3))) void* las3;

__device__ __forceinline__ void gl16(const void* g, void* l) {
    __builtin_amdgcn_global_load_lds((gas1)g, (las3)l, 16, 0, 0);
}
template<int N> __device__ __forceinline__ void vwait() {
    asm volatile("s_waitcnt vmcnt(%0)" :: "n"(N) : "memory");
}
__device__ __forceinline__ void barx() {
    asm volatile("" ::: "memory");
    __builtin_amdgcn_s_barrier();
    asm volatile("" ::: "memory");
}

// ============ pool kernel: 256 thr, 4 waves, TBMx128 tile, BK=32, 3-buf ============
// A [M][Np] fp16 (rows clamped), B [cols][Np] fp16 (actT layout), C [M][cols] fp16
__global__ void __launch_bounds__(256, 3) pool2_k_impl();  // fwd decl dummy (unused)

template<int TBM>
__global__ __launch_bounds__(256, 3) void pool2_k(
    const _Float16* __restrict__ Aw, const _Float16* __restrict__ Bw,
    _Float16* __restrict__ Cp, int M, int Np, u64 c_rs)
{
    constexpr int FM  = TBM / 32;          // wave m-frags (WM=2)
    constexpr int LPS = TBM / 64 + 2;      // gl16 per thread per stage

    __shared__ _Float16 sA[3][TBM][BK];
    __shared__ _Float16 sB[3][128][BK];

    const int t  = threadIdx.x;
    const int m0 = blockIdx.y * TBM;
    const int f0 = blockIdx.x * 128;
    const int lane = t & 63;
    const int wid  = t >> 6;
    const int wm = wid >> 1;     // 0..1
    const int wf = wid & 1;      // 0..1
    const int lm = lane & 15;
    const int lg = lane >> 4;

    f32x4 acc[FM][4];
    #pragma unroll
    for (int i = 0; i < FM; ++i)
        #pragma unroll
        for (int j = 0; j < 4; ++j)
            acc[i][j] = (f32x4)0.0f;

    auto stage = [&](int buf, int ks) {
        #pragma unroll
        for (int j = 0; j < TBM / 64; ++j) {
            int c   = t + j * 256;
            int row = c >> 2;
            int sw  = ((c & 3) ^ ((row >> 1) & 3)) * 8;   // pre-swizzled source chunk
            int rc  = m0 + row; if (rc >= M) rc = M - 1;
            gl16(Aw + (u64)rc * Np + ks * BK + sw,
                 (_Float16*)&sA[buf][0][0] + (u64)c * 8);  // linear dest
        }
        #pragma unroll
        for (int j = 0; j < 2; ++j) {
            int c   = t + j * 256;
            int row = c >> 2;
            int sw  = ((c & 3) ^ ((row >> 1) & 3)) * 8;
            gl16(Bw + (u64)(f0 + row) * Np + ks * BK + sw,
                 (_Float16*)&sB[buf][0][0] + (u64)c * 8);
        }
    };

    auto compute = [&](int buf) {
        const int sa = (lg ^ ((lm >> 1) & 3)) * 8;        // un-swizzle on read
        half8 af[FM], bf[4];
        #pragma unroll
        for (int i = 0; i < FM; ++i)
            af[i] = *(const half8*)&sA[buf][wm * (FM * 16) + i * 16 + lm][sa];
        #pragma unroll
        for (int j = 0; j < 4; ++j)
            bf[j] = *(const half8*)&sB[buf][wf * 64 + j * 16 + lm][sa];
        #pragma unroll
        for (int i = 0; i < FM; ++i)
            #pragma unroll
            for (int j = 0; j < 4; ++j)
                acc[i][j] = __builtin_amdgcn_mfma_f32_16x16x32_f16(af[i], bf[j], acc[i][j], 0, 0, 0);
    };

    const int ke = Np / BK;
    stage(0, 0);
    if (1 < ke) stage(1, 1);
    if (2 < ke) stage(2, 2);
    int cur = 0;
    for (int ks = 0; ks < ke; ++ks) {
        int rem = ke - ks;
        if (rem >= 3)      vwait<2 * LPS>();
        else if (rem == 2) vwait<LPS>();
        else               vwait<0>();
        barx();
        compute(cur);
        barx();
        if (ks + 3 < ke) stage(cur, ks + 3);
        cur = (cur == 2) ? 0 : cur + 1;
    }

    #pragma unroll
    for (int j = 0; j < 4; ++j) {
        int fl = f0 + wf * 64 + j * 16 + lm;
        #pragma unroll
        for (int i = 0; i < FM; ++i) {
            #pragma unroll
            for (int r = 0; r < 4; ++r) {
                int m = m0 + wm * (FM * 16) + i * 16 + lg * 4 + r;
                if (m < M)
                    Cp[(u64)m * c_rs + fl] = (_Float16)acc[i][j][r];
            }
        }
    }
}

// ============ general kernel (sconv / fc) ============
// AMODE: 1 sconv gather (idx via LDS), 2 sconv0 (Fi=3, nk=1),
//        3 fc, 4 fc-enc split-K, 5 sconv rows-folded [Wd3]
template<int AMODE, int EPI, int TBM, int TBF, int WM, int WF>
__global__ __launch_bounds__(256) void gemm_k(
    const _Float16* __restrict__ Aw, u64 a_rs,
    const int* __restrict__ idx, int FiLog,
    const _Float16* __restrict__ Bw,
    const float* __restrict__ bias,
    void* __restrict__ Cp, u64 c_rs, int Mp_out,
    int M, int Np, int F, int flags, int ksp)   // flags: bit0 ELU, bit1 zeroLast
{
    constexpr int FM = TBM / WM / 16;
    constexpr int FF = TBF / WF / 16;
    constexpr int LPS_A = TBM / 64;
    constexpr bool BSM = (TBF < 64);
    constexpr int LPS_B = BSM ? 0 : TBF / 64;
    constexpr int LW0 = LPS_A + (BSM ? 1 : LPS_B);
    constexpr int LWX = LPS_A + LPS_B;
    constexpr int NI = (AMODE == 1) ? TBM : 2;

    __shared__ _Float16 sA[3][TBM][BK];
    __shared__ _Float16 sB[3][TBF][BK];
    __shared__ int sIdx[NI][9];

    const int t  = threadIdx.x;
    const int b  = blockIdx.z;
    const int m0 = blockIdx.y * TBM;
    const int f0 = blockIdx.x * TBF;
    const int lane = t & 63;
    const int wid  = t >> 6;
    const int wm = wid / WF;
    const int wf = wid % WF;
    const int lm = lane & 15;
    const int lg = lane >> 4;
    const int Fi = 1 << FiLog;

    f32x4 acc[FM][FF];
    #pragma unroll
    for (int i = 0; i < FM; ++i)
        #pragma unroll
        for (int j = 0; j < FF; ++j)
            acc[i][j] = (f32x4)0.0f;

    if constexpr (AMODE == 1) {
        for (int i = t; i < TBM * 9; i += 256) {
            int r = i / 9, k = i - r * 9;
            int rc = m0 + r; if (rc >= M) rc = M - 1;
            sIdx[r][k] = idx[rc * 9 + k];
        }
        __syncthreads();
    } else if constexpr (AMODE == 5) {
        if (t < 18) {
            int r = t / 9, k = t - r * 9;
            sIdx[r][k] = idx[((m0 >> 6) + r) * 9 + k];
        }
        __syncthreads();
    }

    auto stage = [&](int buf, int ks) {
        if constexpr (AMODE != 2) {
            #pragma unroll
            for (int j = 0; j < LPS_A; ++j) {
                int c   = t + j * 256;
                int row = c >> 2;
                int sw  = ((c & 3) ^ ((row >> 1) & 3)) * 8;   // pre-swizzled source chunk
                int col = ks * BK + sw;
                const _Float16* src;
                if constexpr (AMODE == 3) {
                    int rc = m0 + row; if (rc >= M) rc = M - 1;
                    src = Aw + (u64)rc * Np + col;
                } else if constexpr (AMODE == 1) {
                    int k = col >> FiLog, fi = col & (Fi - 1);
                    src = Aw + (u64)sIdx[row][k] * a_rs + b * Fi + fi;
                } else if constexpr (AMODE == 4) {
                    int k = col >> FiLog, fi = col & (Fi - 1);
                    src = Aw + (u64)k * a_rs + (m0 + row) * Fi + fi;
                } else {  // 5
                    int k = col >> FiLog, fi = col & (Fi - 1);
                    int bb = (m0 + row) & 63;
                    src = Aw + (u64)sIdx[row >> 6][k] * a_rs + bb * Fi + fi;
                }
                gl16(src, &sA[buf][row][(c & 3) * 8]);   // linear dest
            }
        }
        if constexpr (!BSM) {
            #pragma unroll
            for (int j = 0; j < LPS_B; ++j) {
                int c   = t + j * 256;
                int row = c >> 2;
                int sw  = ((c & 3) ^ ((row >> 1) & 3)) * 8;
                gl16(Bw + (u64)(f0 + row) * Np + ks * BK + sw, &sB[buf][row][(c & 3) * 8]);
            }
        } else {
            if (wid == 0) {
                int c   = t;
                int row = c >> 2;
                int sw  = ((c & 3) ^ ((row >> 1) & 3)) * 8;
                gl16(Bw + (u64)(f0 + row) * Np + ks * BK + sw, &sB[buf][row][(c & 3) * 8]);
            }
        }
    };

    auto compute = [&](int buf) {
        const int sa = (lg ^ ((lm >> 1) & 3)) * 8;   // un-swizzle on read
        half8 af[FM], bf[FF];
        #pragma unroll
        for (int i = 0; i < FM; ++i)
            af[i] = *(const half8*)&sA[buf][wm * (FM * 16) + i * 16 + lm][sa];
        #pragma unroll
        for (int j = 0; j < FF; ++j)
            bf[j] = *(const half8*)&sB[buf][wf * (FF * 16) + j * 16 + lm][sa];
        #pragma unroll
        for (int i = 0; i < FM; ++i)
            #pragma unroll
            for (int j = 0; j < FF; ++j)
                acc[i][j] = __builtin_amdgcn_mfma_f32_16x16x32_f16(af[i], bf[j], acc[i][j], 0, 0, 0);
    };

    if constexpr (AMODE == 2) {
        stage(0, 0);   // B only
        {
            int row = t >> 1;
            int base = (t & 1) * 16;
            int rg = m0 + row;
            #pragma unroll
            for (int q = 0; q < 16; ++q) {
                int n = base + q;
                _Float16 val = (_Float16)0.f;
                if (rg < M && n < 27) {
                    int k = n / 3, fi = n - k * 3;
                    val = Aw[(u64)idx[rg * 9 + k] * a_rs + b * 3 + fi];
                }
                int ch = (n >> 3) ^ ((row >> 1) & 3);
                sA[0][row][ch * 8 + (n & 7)] = val;   // store swizzled
            }
        }
        __syncthreads();
        compute(0);
    } else {
        int kb = 0, ke = Np / BK;
        if constexpr (AMODE == 4) { kb = b * ksp; ke = kb + ksp; }
        stage(0, kb);
        if (kb + 1 < ke) stage(1, kb + 1);
        if (kb + 2 < ke) stage(2, kb + 2);
        int cur = 0;
        for (int ks = kb; ks < ke; ++ks) {
            int rem = ke - ks;
            if (rem >= 3) {
                if constexpr (LW0 == LWX) vwait<2 * LW0>();
                else { if (wid == 0) vwait<2 * LW0>(); else vwait<2 * LWX>(); }
            } else if (rem == 2) {
                if constexpr (LW0 == LWX) vwait<LW0>();
                else { if (wid == 0) vwait<LW0>(); else vwait<LWX>(); }
            } else {
                vwait<0>();
            }
            barx();
            compute(cur);
            barx();
            if (ks + 3 < ke) stage(cur, ks + 3);
            cur = (cur == 2) ? 0 : cur + 1;
        }
    }

    #pragma unroll
    for (int j = 0; j < FF; ++j) {
        int fl = f0 + wf * (FF * 16) + j * 16 + lm;
        float bv = 0.f;
        if (bias != nullptr && fl < F) bv = bias[fl];
        #pragma unroll
        for (int i = 0; i < FM; ++i) {
            #pragma unroll
            for (int r = 0; r < 4; ++r) {
                int m = m0 + wm * (FM * 16) + i * 16 + lg * 4 + r;
                float v = acc[i][j][r] + bv;
                if (flags & 1) v = (v > 0.f) ? v : expm1f(v);
                if constexpr (EPI == EPI_NAT) {
                    if (m < M && fl < F)
                        ((_Float16*)Cp)[(u64)m * c_rs + fl] = (_Float16)v;
                } else if constexpr (EPI == EPI_TR) {
                    if (m < Mp_out && fl < F) {
                        float o = (m < M && !((flags & 2) && m == M - 1)) ? v : 0.f;
                        ((_Float16*)Cp)[(u64)b * c_rs + (u64)fl * Mp_out + m] = (_Float16)o;
                    }
                } else if constexpr (EPI == EPI_FCD) {
                    if (m < M && fl < F)
                        ((_Float16*)Cp)[((u64)m * 256 + (fl & 255)) * 32 + (fl >> 8)] = (_Float16)v;
                } else if constexpr (EPI == EPI_PART) {
                    if (m < M && fl < F)
                        ((float*)Cp)[(u64)b * c_rs + (u64)m * F + fl] = v;
                } else {  // EPI_OUT (rows folded: m = v*64+b)
                    if (m < M && fl < F) {
                        int vo = m >> 6, bb = m & 63;
                        float o = ((flags & 2) && vo == Mp_out - 1) ? 0.f : v;
                        ((float*)Cp)[((u64)bb * Mp_out + vo) * 3 + fl] = o;
                    }
                }
            }
        }
    }
}

// ---- fused weight conversion ----
struct CvtPtrs { const float* p[18]; };

constexpr int CV_R[18]  = {1257,5024,315,1257,80,315,21,80,  64,64,128,256,256,5376,128,64,64,16};
constexpr int CV_N[18]  = {5024,1257,1257,315,315,80,80,21,  27,576,576,1152,5376,256,2304,1152,576,576};
constexpr int CV_NP[18] = {5120,1280,1280,320,320,96,96,32,  32,576,576,1152,5376,256,2304,1152,576,576};
constexpr int CV_F[18]  = {0,0,0,0,0,0,0,0,  64,64,128,256,256,5376,128,64,64,3};

constexpr u64 cv_elems(int i) { return (u64)CV_R[i] * CV_NP[i]; }
constexpr u64 cv_off(int i) { u64 o = 0; for (int j = 0; j < i; ++j) o += (cv_elems(j) + 255) & ~(u64)255; return o; }
constexpr int cv_blk(int i) { return (int)((cv_elems(i) + 255) >> 8); }
constexpr int cv_start(int i) { int s = 0; for (int j = 0; j < i; ++j) s += cv_blk(j); return s; }

__global__ __launch_bounds__(256) void cvt_all(CvtPtrs ps, _Float16* __restrict__ dst)
{
    const int bx = blockIdx.x, t = threadIdx.x;
    #pragma unroll
    for (int i = 0; i < 18; ++i) {
        if (bx >= cv_start(i) && bx < cv_start(i + 1)) {
            const u64 e = (u64)(bx - cv_start(i)) * 256 + t;
            if (e < cv_elems(i)) {
                const int NP = CV_NP[i], N = CV_N[i], Fo = CV_F[i];
                int row = (int)(e / (u64)NP);
                int col = (int)(e - (u64)row * NP);
                float v = 0.f;
                const float* s = ps.p[i];
                if (Fo == 0) { if (col < N) v = s[(u64)row * N + col]; }
                else         { if (col < N && row < Fo) v = s[(u64)col * Fo + row]; }
                dst[cv_off(i) + e] = (_Float16)v;
            }
        }
    }
}

__global__ void cvt_x(const float* __restrict__ src, _Float16* __restrict__ dst)
{
    int i = blockIdx.x * 256 + threadIdx.x;
    if (i >= 64 * 5024 * 3) return;
    int v = i / 192;
    int r = i - v * 192;
    int b = r / 3, c = r - b * 3;
    dst[i] = (_Float16)src[((u64)b * 5024 + v) * 3 + c];
}

__global__ void reduce_fce(const float* __restrict__ part, const float* __restrict__ bias,
                           _Float16* __restrict__ z)
{
    int i = blockIdx.x * 256 + threadIdx.x;  // 64*256
    int fl = i & 255;
    float s = bias[fl];
    #pragma unroll
    for (int p = 0; p < 8; ++p) s += part[(u64)p * 16384 + i];
    z[i] = (_Float16)s;
}

extern "C" void kernel_launch(void* const* d_in, const int* in_sizes, int n_in,
                              void* d_out, int out_size, void* d_ws, size_t ws_size,
                              hipStream_t stream)
{
    const float* x  = (const float*)d_in[0];
    const int* s0 = (const int*)d_in[1];
    const int* s1 = (const int*)d_in[2];
    const int* s2 = (const int*)d_in[3];
    const int* s3 = (const int*)d_in[4];
    const float* be0 = (const float*)d_in[14];
    const float* be1 = (const float*)d_in[16];
    const float* be2 = (const float*)d_in[18];
    const float* be3 = (const float*)d_in[20];
    const float* fceb = (const float*)d_in[22];
    const float* fcdb = (const float*)d_in[24];
    const float* bd0 = (const float*)d_in[26];
    const float* bd1 = (const float*)d_in[28];
    const float* bd2 = (const float*)d_in[30];
    const float* bd3 = (const float*)d_in[32];

    _Float16* W = (_Float16*)d_ws;
    size_t off = 0;
    auto alloc = [&](size_t e) { size_t o = off; off += (e + 255) & ~(size_t)255; return o; };

    const size_t oActV = alloc((size_t)5024 * 4096);   // [vertex][(b,f)]
    const size_t oActT = alloc((size_t)4096 * 5120);   // [(b,f)][vertex_padded]
    const size_t oZ    = alloc((size_t)64 * 256);
    const size_t oPart = alloc((size_t)8 * 64 * 256 * 2);  // fp32 partials
    const size_t oU3in = alloc((size_t)16384 * 32);
    const size_t oXp   = alloc((size_t)5024 * 192);
    const size_t oCvt  = alloc((size_t)(cv_off(17) + ((cv_elems(17) + 255) & ~(u64)255)));
    auto wofs = [&](int i) { return oCvt + (size_t)cv_off(i); };

    // ---- conversions ----
    cvt_x<<<dim3((64 * 5024 * 3 + 255) / 256), 256, 0, stream>>>(x, W + oXp);
    {
        CvtPtrs ps;
        ps.p[0] = (const float*)d_in[5];   // D0
        ps.p[1] = (const float*)d_in[6];   // U0
        ps.p[2] = (const float*)d_in[7];   // D1
        ps.p[3] = (const float*)d_in[8];   // U1
        ps.p[4] = (const float*)d_in[9];   // D2
        ps.p[5] = (const float*)d_in[10];  // U2
        ps.p[6] = (const float*)d_in[11];  // D3
        ps.p[7] = (const float*)d_in[12];  // U3
        ps.p[8] = (const float*)d_in[13];  // We0
        ps.p[9] = (const float*)d_in[15];  // We1
        ps.p[10] = (const float*)d_in[17]; // We2
        ps.p[11] = (const float*)d_in[19]; // We3
        ps.p[12] = (const float*)d_in[21]; // fceW
        ps.p[13] = (const float*)d_in[23]; // fcdW
        ps.p[14] = (const float*)d_in[25]; // Wd0
        ps.p[15] = (const float*)d_in[27]; // Wd1
        ps.p[16] = (const float*)d_in[29]; // Wd2
        ps.p[17] = (const float*)d_in[31]; // Wd3
        cvt_all<<<dim3(cv_start(18)), 256, 0, stream>>>(ps, W + oCvt);
    }
    hipMemsetAsync(W + oU3in, 0, (size_t)16384 * 32 * sizeof(_Float16), stream);

    #define GEMM(AM, EP, BM_, BF_, WM_, WF_, gx, gy, gz, Aw_, ars_, idx_, FiL_, Bw_, bias_, Cp_, crs_, Mp_, M_, Np_, F_, fl_, ksp_) \
        gemm_k<AM, EP, BM_, BF_, WM_, WF_><<<dim3(gx, gy, gz), 256, 0, stream>>>( \
            Aw_, ars_, idx_, FiL_, Bw_, bias_, Cp_, crs_, Mp_, M_, Np_, F_, fl_, ksp_)
    #define POOL(TBM_, gx, gy, Aw_, Bw_, Cp_, M_, Np_, crs_) \
        pool2_k<TBM_><<<dim3(gx, gy), 256, 0, stream>>>(Aw_, Bw_, Cp_, M_, Np_, crs_)

    // ---- encoder ----
    GEMM(2, EPI_TR, 128, 64, 2, 2, 1, 40, 64, W + oXp, 192, s0, 0,
         W + wofs(8), be0, W + oActT, (u64)64 * 5120, 5120, 5024, 32, 64, 3, 0);
    POOL(64, 32, 20, W + wofs(0), W + oActT, W + oActV, 1257, 5120, 4096);
    GEMM(1, EPI_TR, 128, 64, 2, 2, 1, 10, 64, W + oActV, 4096, s1, 6,
         W + wofs(9), be1, W + oActT, (u64)64 * 1280, 1280, 1257, 576, 64, 3, 0);
    POOL(64, 32, 5, W + wofs(2), W + oActT, W + oActV, 315, 1280, 4096);
    GEMM(1, EPI_TR, 128, 64, 2, 2, 2, 3, 64, W + oActV, 4096, s2, 6,
         W + wofs(10), be2, W + oActT, (u64)128 * 320, 320, 315, 576, 128, 3, 0);
    POOL(64, 64, 2, W + wofs(4), W + oActT, W + oActV, 80, 320, 8192);
    GEMM(1, EPI_TR, 128, 64, 2, 2, 4, 1, 64, W + oActV, 8192, s3, 7,
         W + wofs(11), be3, W + oActT, (u64)256 * 96, 96, 80, 1152, 256, 3, 0);
    POOL(64, 128, 1, W + wofs(6), W + oActT, W + oActV, 21, 96, 16384);
    // ---- bottleneck ----
    GEMM(4, EPI_PART, 64, 64, 2, 2, 4, 1, 8, W + oActV, 16384, nullptr, 8,
         W + wofs(12), nullptr, W + oPart, (u64)64 * 256, 0, 64, 5376, 256, 0, 21);
    reduce_fce<<<dim3(64), 256, 0, stream>>>((const float*)(W + oPart), fceb, W + oZ);
    GEMM(3, EPI_FCD, 64, 128, 2, 2, 42, 1, 1, W + oZ, 0, nullptr, 0,
         W + wofs(13), fcdb, W + oU3in, 0, 0, 64, 256, 5376, 0, 0);
    // ---- decoder ----
    POOL(64, 128, 2, W + wofs(7), W + oU3in, W + oActV, 80, 32, 16384);
    GEMM(1, EPI_TR, 128, 64, 2, 2, 2, 1, 64, W + oActV, 16384, s3, 8,
         W + wofs(14), bd0, W + oActT, (u64)128 * 96, 96, 80, 2304, 128, 3, 0);
    POOL(64, 64, 5, W + wofs(5), W + oActT, W + oActV, 315, 96, 8192);
    GEMM(1, EPI_TR, 128, 64, 2, 2, 1, 3, 64, W + oActV, 8192, s2, 7,
         W + wofs(15), bd1, W + oActT, (u64)64 * 320, 320, 315, 1152, 64, 3, 0);
    POOL(64, 32, 20, W + wofs(3), W + oActT, W + oActV, 1257, 320, 4096);
    GEMM(1, EPI_TR, 128, 64, 2, 2, 1, 10, 64, W + oActV, 4096, s1, 6,
         W + wofs(16), bd2, W + oActT, (u64)64 * 1280, 1280, 1257, 576, 64, 3, 0);
    POOL(128, 32, 40, W + wofs(1), W + oActT, W + oActV, 5024, 1280, 4096);
    GEMM(5, EPI_OUT, 128, 16, 4, 1, 1, 2512, 1, W + oActV, 4096, s0, 6,
         W + wofs(17), bd3, d_out, 0, 5024, 321536, 576, 3, 2, 0);
    #undef GEMM
    #undef POOL
}